// Round 1
// baseline (1034.644 us; speedup 1.0000x reference)
//
#include <hip/hip_runtime.h>

#define BB 16
#define NN 8400
#define GG 100
#define CC 80
#define KTOP 13
#define EPSF 1e-7f
#define INFC 1e8f

static constexpr size_t kO_LAB  = 0;
static constexpr size_t kO_W    = (size_t)BB * NN;               // 134400
static constexpr size_t kO_BB   = kO_W + (size_t)BB * NN * CC;   // 10886400
static constexpr size_t kO_SC   = kO_BB + (size_t)BB * NN * 4;   // 11424000
static constexpr size_t kO_MET  = kO_SC + (size_t)BB * NN * CC;  // 22176000
static constexpr size_t kO_FG   = kO_MET + (size_t)BB * NN;      // 22310400
static constexpr size_t kO_NUM  = kO_FG + (size_t)BB * NN;       // 22444800
static constexpr size_t kO_DYNW = kO_NUM + CC;                   // 22444880
static constexpr size_t kO_AREA = kO_DYNW + CC;                  // 22444960

// monotone float->uint mapping (total order matching float <)
__device__ __forceinline__ unsigned f2u(float x) {
    unsigned b = __float_as_uint(x);
    return (b & 0x80000000u) ? ~b : (b | 0x80000000u);
}

// Pair cost + |giou|*is_in, exactly mirroring the reference math.
__device__ __forceinline__ void pair_cost_iou(
    float px, float py, float st,
    float p0, float p1, float p2, float p3,
    float g0, float g1, float g2, float g3,
    float lg, float flag,
    float& cost, float& piou)
{
    // inside-gt test
    float l = px - g0, t = py - g1, r = g2 - px, d = g3 - py;
    float mn = fminf(fminf(l, t), fminf(r, d));
    float is_in = (mn > 0.0f) ? flag : 0.0f;
    // soft center prior
    float gcx = (g0 + g2) * 0.5f, gcy = (g1 + g3) * 0.5f;
    float dx = px - gcx, dy = py - gcy;
    float dist = sqrtf(dx * dx + dy * dy) / st * is_in;
    float scp = powf(10.0f, dist - 3.0f) * is_in;
    // giou
    float ix1 = fmaxf(p0, g0), iy1 = fmaxf(p1, g1);
    float ix2 = fminf(p2, g2), iy2 = fminf(p3, g3);
    float ow = fmaxf(ix2 - ix1, 0.0f), oh = fmaxf(iy2 - iy1, 0.0f);
    float ov = ow * oh;
    float a1 = (p2 - p0) * (p3 - p1);
    float a2 = (g2 - g0) * (g3 - g1);
    float uni = fmaxf(a1 + a2 - ov, EPSF);
    float iou = ov / uni;
    float ex1 = fminf(p0, g0), ey1 = fminf(p1, g1);
    float ex2 = fmaxf(p2, g2), ey2 = fmaxf(p3, g3);
    float ew = fmaxf(ex2 - ex1, 0.0f), eh = fmaxf(ey2 - ey1, 0.0f);
    float enc = fmaxf(ew * eh, EPSF);
    float giou = iou - (enc - uni) / enc;
    piou = fabsf(giou * is_in);
    float iou_cost = -logf(piou + EPSF) * 3.0f;
    // classification cost
    float sig = 1.0f / (1.0f + expf(-lg));
    float sc = piou - sig;
    float asc = fabsf(sc);
    float bce = fmaxf(lg, 0.0f) - lg * piou + log1pf(expf(-fabsf(lg)));
    float cls = bce * expf(asc - 1.0f) * asc;
    float cc = cls + iou_cost + scp;
    cost = (is_in > 0.0f) ? cc : INFC;
}

__device__ __forceinline__ unsigned long long block_max_u64(
    unsigned long long v, unsigned long long* s_red, int tid)
{
    #pragma unroll
    for (int off = 32; off > 0; off >>= 1) {
        unsigned long long o = __shfl_down(v, off, 64);
        if (o > v) v = o;
    }
    if ((tid & 63) == 0) s_red[tid >> 6] = v;
    __syncthreads();
    if (tid == 0) {
        unsigned long long m = s_red[0];
        for (int i = 1; i < 4; ++i) if (s_red[i] > m) m = s_red[i];
        s_red[0] = m;
    }
    __syncthreads();
    return s_red[0];
}

__device__ __forceinline__ unsigned long long block_min_u64(
    unsigned long long v, unsigned long long* s_red, int tid)
{
    #pragma unroll
    for (int off = 32; off > 0; off >>= 1) {
        unsigned long long o = __shfl_down(v, off, 64);
        if (o < v) v = o;
    }
    if ((tid & 63) == 0) s_red[tid >> 6] = v;
    __syncthreads();
    if (tid == 0) {
        unsigned long long m = s_red[0];
        for (int i = 1; i < 4; ++i) if (s_red[i] < m) m = s_red[i];
        s_red[0] = m;
    }
    __syncthreads();
    return s_red[0];
}

// K1: one workgroup per (b,g). Computes cost/iou rows, dyn_k, and scatters matches.
__global__ __launch_bounds__(256) void k1_match(
    const float* __restrict__ pred_bboxes,
    const float* __restrict__ pred_scores,
    const float* __restrict__ priors,
    const int*   __restrict__ gt_labels,
    const float* __restrict__ gt_bboxes,
    const float* __restrict__ pad_flag,
    int*   __restrict__ match_count,
    int*   __restrict__ match_g,
    float* __restrict__ match_iou)
{
    __shared__ float s_cost[NN];
    __shared__ float s_iou[NN];
    __shared__ unsigned long long s_red[4];
    __shared__ int   s_sav_idx[KTOP];
    __shared__ float s_sav_val[KTOP];

    int bg = blockIdx.x;
    int b = bg / GG, g = bg % GG;
    int tid = threadIdx.x;

    float flag = pad_flag[b * GG + g];
    if (flag == 0.0f) return;   // invalid gt: contributes nothing (uniform exit)

    float g0 = gt_bboxes[(b * GG + g) * 4 + 0];
    float g1 = gt_bboxes[(b * GG + g) * 4 + 1];
    float g2 = gt_bboxes[(b * GG + g) * 4 + 2];
    float g3 = gt_bboxes[(b * GG + g) * 4 + 3];
    int lab = gt_labels[b * GG + g];

    for (int n = tid; n < NN; n += 256) {
        float px = priors[n * 4 + 0];
        float py = priors[n * 4 + 1];
        float st = priors[n * 4 + 2];
        const float* pb = pred_bboxes + (size_t)(b * NN + n) * 4;
        float lg = pred_scores[(size_t)(b * NN + n) * CC + lab];
        float cost, piou;
        pair_cost_iou(px, py, st, pb[0], pb[1], pb[2], pb[3],
                      g0, g1, g2, g3, lg, flag, cost, piou);
        s_cost[n] = cost;
        s_iou[n]  = piou;
    }
    __syncthreads();

    // Phase 2: top-13 ious, summed descending (matches top_k(...).sum(-1))
    float ksum = 0.0f;
    for (int it = 0; it < KTOP; ++it) {
        unsigned long long best = 0ull;
        for (int n = tid; n < NN; n += 256) {
            unsigned long long key =
                ((unsigned long long)f2u(s_iou[n]) << 32) | (unsigned)n;
            if (key > best) best = key;
        }
        best = block_max_u64(best, s_red, tid);
        int bi = (int)(best & 0xffffffffu);
        unsigned ub = (unsigned)(best >> 32);
        float bv = __uint_as_float((ub & 0x80000000u) ? (ub & 0x7fffffffu) : ~ub);
        ksum += bv;
        if (tid == 0) {
            s_sav_idx[it] = bi;
            s_sav_val[it] = bv;
            s_iou[bi] = -1.0f;   // exclude (all real ious >= 0)
        }
        __syncthreads();
    }
    // restore excluded ious (needed for match_iou scatter)
    if (tid < KTOP) s_iou[s_sav_idx[tid]] = s_sav_val[tid];
    __syncthreads();

    int dyn_k = (int)ksum;          // trunc toward zero, ksum >= 0
    if (dyn_k < 1) dyn_k = 1;       // clip(..., 1, None)

    // Phase 3: dyn_k smallest (cost, idx) lexicographic — matches stable argsort rank
    for (int it = 0; it < dyn_k; ++it) {
        unsigned long long best = ~0ull;
        for (int n = tid; n < NN; n += 256) {
            unsigned long long key =
                ((unsigned long long)f2u(s_cost[n]) << 32) | (unsigned)n;
            if (key < best) best = key;
        }
        best = block_min_u64(best, s_red, tid);
        int bi = (int)(best & 0xffffffffu);
        if (tid == 0) {
            s_cost[bi] = __builtin_inff();   // exclude from later rounds
            int idx = b * NN + bi;
            atomicAdd(&match_count[idx], 1);
            match_g[idx]  = g;               // valid when count==1 (single writer)
            match_iou[idx] = s_iou[bi];
        }
        __syncthreads();
    }
}

// K2: per-prior resolve: single/multi-match, write labels/fg/metrics/bboxes, class counts.
__global__ __launch_bounds__(256) void k2_resolve(
    const float* __restrict__ pred_bboxes,
    const float* __restrict__ pred_scores,
    const float* __restrict__ priors,
    const int*   __restrict__ gt_labels,
    const float* __restrict__ gt_bboxes,
    const float* __restrict__ pad_flag,
    const int*   __restrict__ match_count,
    const int*   __restrict__ match_g,
    const float* __restrict__ match_iou,
    int*   __restrict__ r_lab,
    float* __restrict__ r_miou,
    int*   __restrict__ class_num,
    float* __restrict__ out)
{
    int i = blockIdx.x * 256 + threadIdx.x;
    if (i >= BB * NN) return;
    int b = i / NN, n = i % NN;
    int cnt = match_count[i];

    int lab = CC;
    float miou = 0.0f;
    int gstar = -1;

    if (cnt == 1) {
        gstar = match_g[i];
        miou  = match_iou[i];
    } else if (cnt > 1) {
        // multi-match: onehot of argmin over full cost row (first-tie wins)
        float px = priors[n * 4 + 0];
        float py = priors[n * 4 + 1];
        float st = priors[n * 4 + 2];
        const float* pb = pred_bboxes + (size_t)i * 4;
        float p0 = pb[0], p1 = pb[1], p2 = pb[2], p3 = pb[3];
        float bestc = __builtin_inff();
        float besti = 0.0f;
        int bestg = 0;
        for (int g = 0; g < GG; ++g) {
            float flag = pad_flag[b * GG + g];
            float g0 = gt_bboxes[(b * GG + g) * 4 + 0];
            float g1 = gt_bboxes[(b * GG + g) * 4 + 1];
            float g2 = gt_bboxes[(b * GG + g) * 4 + 2];
            float g3 = gt_bboxes[(b * GG + g) * 4 + 3];
            int lb = gt_labels[b * GG + g];
            float lg = pred_scores[(size_t)i * CC + lb];
            float cost, piou;
            pair_cost_iou(px, py, st, p0, p1, p2, p3,
                          g0, g1, g2, g3, lg, flag, cost, piou);
            if (cost < bestc) { bestc = cost; bestg = g; besti = piou; }
        }
        gstar = bestg;
        miou  = besti;
    }

    bool fg = (cnt > 0);
    if (fg) {
        lab = gt_labels[b * GG + gstar];
        atomicAdd(&class_num[lab], 1);
    }
    r_lab[i]  = lab;
    r_miou[i] = miou;

    out[kO_LAB + i] = (float)lab;
    out[kO_FG  + i] = fg ? 1.0f : 0.0f;
    out[kO_MET + i] = fg ? miou : 0.0f;

    float b0 = 0.0f, b1 = 0.0f, b2 = 0.0f, b3 = 0.0f;
    if (fg) {
        const float* gb = gt_bboxes + (size_t)(b * GG + gstar) * 4;
        b0 = gb[0]; b1 = gb[1]; b2 = gb[2]; b3 = gb[3];
    }
    out[kO_BB + (size_t)i * 4 + 0] = b0;
    out[kO_BB + (size_t)i * 4 + 1] = b1;
    out[kO_BB + (size_t)i * 4 + 2] = b2;
    out[kO_BB + (size_t)i * 4 + 3] = b3;
}

// K3: class counts -> dynamic weights
__global__ void k3_weights(const int* __restrict__ class_num,
                           float* __restrict__ dynw,
                           float* __restrict__ out)
{
    __shared__ float s_max;
    int c = threadIdx.x;
    if (c == 0) {
        int m = 0;
        for (int i = 0; i < CC; ++i) m = max(m, class_num[i]);
        s_max = (float)m;
    }
    __syncthreads();
    if (c < CC) {
        int num = class_num[c];
        float w = (num > 0) ? s_max / fmaxf((float)num, 1.0f) : 1.0f;
        dynw[c] = w;
        out[kO_NUM  + c] = (float)num;
        out[kO_DYNW + c] = w;
    }
}

// K4: fill assigned_scores and assigned_labels_weights (coalesced over B*N*C)
__global__ __launch_bounds__(256) void k4_fill(
    const int*   __restrict__ r_lab,
    const float* __restrict__ r_miou,
    const float* __restrict__ dynw,
    float* __restrict__ out)
{
    size_t idx = (size_t)blockIdx.x * 256 + threadIdx.x;
    if (idx >= (size_t)BB * NN * CC) return;
    int i = (int)(idx / CC);
    int c = (int)(idx % CC);
    int lab = r_lab[i];
    bool fg = (lab < CC);
    float miou = r_miou[i];
    out[kO_SC + idx] = (lab == c) ? miou : 0.0f;       // lab==c implies fg
    out[kO_W  + idx] = fg ? dynw[c] : 1.0f;
}

// K5: area_dist (3, B, G)
__global__ void k5_area(const float* __restrict__ gt_area,
                        const float* __restrict__ area_rule,
                        const float* __restrict__ pad_flag,
                        float* __restrict__ out)
{
    int idx = blockIdx.x * 256 + threadIdx.x;
    if (idx >= 3 * BB * GG) return;
    int z = idx / (BB * GG);
    int rem = idx % (BB * GG);
    float ga = gt_area[rem];
    float lo = area_rule[z] * area_rule[z];
    float hi = area_rule[z + 1] * area_rule[z + 1];
    bool v = (ga >= lo) && (ga < hi) && (pad_flag[rem] > 0.0f);
    out[kO_AREA + idx] = v ? 1.0f : 0.0f;
}

extern "C" void kernel_launch(void* const* d_in, const int* in_sizes, int n_in,
                              void* d_out, int out_size, void* d_ws, size_t ws_size,
                              hipStream_t stream)
{
    const float* pred_bboxes = (const float*)d_in[0];
    const float* pred_scores = (const float*)d_in[1];
    const float* priors      = (const float*)d_in[2];
    const int*   gt_labels   = (const int*)d_in[3];
    const float* gt_bboxes   = (const float*)d_in[4];
    const float* pad_flag    = (const float*)d_in[5];
    const float* gt_area     = (const float*)d_in[6];
    const float* area_rule   = (const float*)d_in[7];
    float* out = (float*)d_out;

    // workspace layout (match_count + class_num first so one memset zeroes both)
    char* w = (char*)d_ws;
    int*   match_count = (int*)w;   w += (size_t)BB * NN * 4;
    int*   class_num   = (int*)w;   w += (size_t)CC * 4;
    int*   match_g     = (int*)w;   w += (size_t)BB * NN * 4;
    float* match_iou   = (float*)w; w += (size_t)BB * NN * 4;
    int*   r_lab       = (int*)w;   w += (size_t)BB * NN * 4;
    float* r_miou      = (float*)w; w += (size_t)BB * NN * 4;
    float* dynw        = (float*)w; w += (size_t)CC * 4;

    hipMemsetAsync(d_ws, 0, (size_t)(BB * NN + CC) * 4, stream);

    k1_match<<<BB * GG, 256, 0, stream>>>(
        pred_bboxes, pred_scores, priors, gt_labels, gt_bboxes, pad_flag,
        match_count, match_g, match_iou);

    k2_resolve<<<(BB * NN + 255) / 256, 256, 0, stream>>>(
        pred_bboxes, pred_scores, priors, gt_labels, gt_bboxes, pad_flag,
        match_count, match_g, match_iou, r_lab, r_miou, class_num, out);

    k3_weights<<<1, 128, 0, stream>>>(class_num, dynw, out);

    k4_fill<<<(int)(((size_t)BB * NN * CC + 255) / 256), 256, 0, stream>>>(
        r_lab, r_miou, dynw, out);

    k5_area<<<(3 * BB * GG + 255) / 256, 256, 0, stream>>>(
        gt_area, area_rule, pad_flag, out);
}

// Round 2
// 353.725 us; speedup vs baseline: 2.9250x; 2.9250x over previous
//
#include <hip/hip_runtime.h>

typedef unsigned long long u64;

#define BB 16
#define NN 8400
#define GG 100
#define CC 80
#define KTOP 13
#define EPSF 1e-7f
#define INFC 1e8f
#define MAXMULTI (BB * GG * KTOP / 2)   // cnt>=2 each consumes >=2 of <=20800 matches

static constexpr size_t kO_LAB  = 0;
static constexpr size_t kO_W    = (size_t)BB * NN;               // 134400
static constexpr size_t kO_BB   = kO_W + (size_t)BB * NN * CC;   // 10886400
static constexpr size_t kO_SC   = kO_BB + (size_t)BB * NN * 4;   // 11424000
static constexpr size_t kO_MET  = kO_SC + (size_t)BB * NN * CC;  // 22176000
static constexpr size_t kO_FG   = kO_MET + (size_t)BB * NN;      // 22310400
static constexpr size_t kO_NUM  = kO_FG + (size_t)BB * NN;       // 22444800
static constexpr size_t kO_DYNW = kO_NUM + CC;                   // 22444880
static constexpr size_t kO_AREA = kO_DYNW + CC;                  // 22444960

// monotone float->uint mapping (total order matching float <)
__device__ __forceinline__ unsigned f2u(float x) {
    unsigned b = __float_as_uint(x);
    return (b & 0x80000000u) ? ~b : (b | 0x80000000u);
}
__device__ __forceinline__ float u2f(unsigned e) {
    return __uint_as_float((e & 0x80000000u) ? (e & 0x7fffffffu) : ~e);
}

// Pair cost + |giou|*is_in. piou uses only basic arith (it is an output);
// cost-only math uses fast transcendentals (only affects discrete ranking).
__device__ __forceinline__ void pair_cost_iou(
    float px, float py, float st,
    float p0, float p1, float p2, float p3,
    float g0, float g1, float g2, float g3,
    float lg, float flag,
    float& cost, float& piou)
{
    // inside-gt test
    float l = px - g0, t = py - g1, r = g2 - px, d = g3 - py;
    float mn = fminf(fminf(l, t), fminf(r, d));
    float is_in = (mn > 0.0f) ? flag : 0.0f;
    // soft center prior: 10^(dist-3) = exp2((dist-3)*log2(10))
    float gcx = (g0 + g2) * 0.5f, gcy = (g1 + g3) * 0.5f;
    float dx = px - gcx, dy = py - gcy;
    float dist = sqrtf(dx * dx + dy * dy) / st * is_in;
    float scp = exp2f((dist - 3.0f) * 3.32192809488736f) * is_in;
    // giou (exact basic arith)
    float ix1 = fmaxf(p0, g0), iy1 = fmaxf(p1, g1);
    float ix2 = fminf(p2, g2), iy2 = fminf(p3, g3);
    float ow = fmaxf(ix2 - ix1, 0.0f), oh = fmaxf(iy2 - iy1, 0.0f);
    float ov = ow * oh;
    float a1 = (p2 - p0) * (p3 - p1);
    float a2 = (g2 - g0) * (g3 - g1);
    float uni = fmaxf(a1 + a2 - ov, EPSF);
    float iou = ov / uni;
    float ex1 = fminf(p0, g0), ey1 = fminf(p1, g1);
    float ex2 = fmaxf(p2, g2), ey2 = fmaxf(p3, g3);
    float ew = fmaxf(ex2 - ex1, 0.0f), eh = fmaxf(ey2 - ey1, 0.0f);
    float enc = fmaxf(ew * eh, EPSF);
    float giou = iou - (enc - uni) / enc;
    piou = fabsf(giou * is_in);
    float iou_cost = -__logf(piou + EPSF) * 3.0f;
    // classification cost
    float sig = 1.0f / (1.0f + __expf(-lg));
    float sc = piou - sig;
    float asc = fabsf(sc);
    float bce = fmaxf(lg, 0.0f) - lg * piou + log1pf(__expf(-fabsf(lg)));
    float cls = bce * __expf(asc - 1.0f) * asc;
    float cc = cls + iou_cost + scp;
    cost = (is_in > 0.0f) ? cc : INFC;
}

// block reduce over one u64 per thread (256 threads); 2 barriers; result uniform
__device__ __forceinline__ u64 block_max_u64(u64 v, u64* s_red, int tid) {
    #pragma unroll
    for (int off = 32; off > 0; off >>= 1) {
        u64 o = __shfl_down(v, off, 64);
        if (o > v) v = o;
    }
    __syncthreads();                       // protect s_red WAR from prev round
    if ((tid & 63) == 0) s_red[tid >> 6] = v;
    __syncthreads();
    u64 m = s_red[0];
    #pragma unroll
    for (int i = 1; i < 4; ++i) if (s_red[i] > m) m = s_red[i];
    return m;
}
__device__ __forceinline__ u64 block_min_u64(u64 v, u64* s_red, int tid) {
    #pragma unroll
    for (int off = 32; off > 0; off >>= 1) {
        u64 o = __shfl_down(v, off, 64);
        if (o < v) v = o;
    }
    __syncthreads();
    if ((tid & 63) == 0) s_red[tid >> 6] = v;
    __syncthreads();
    u64 m = s_red[0];
    #pragma unroll
    for (int i = 1; i < 4; ++i) if (s_red[i] < m) m = s_red[i];
    return m;
}

// K1: one workgroup per (b,g). Register-resident top-13 lists; head-merge rounds.
__global__ __launch_bounds__(256, 3) void k1_match(
    const float* __restrict__ pred_bboxes,
    const float* __restrict__ pred_scores,
    const float* __restrict__ priors,
    const int*   __restrict__ gt_labels,
    const float* __restrict__ gt_bboxes,
    const float* __restrict__ pad_flag,
    int*   __restrict__ match_count,
    int*   __restrict__ match_g,
    float* __restrict__ match_iou)
{
    __shared__ float s_iou[NN];            // 33.6 KB
    __shared__ u64   s_red[4];
    __shared__ int   s_win[KTOP];

    int bg = blockIdx.x;
    int b = bg / GG, g = bg % GG;
    int tid = threadIdx.x;

    float flag = pad_flag[bg];
    if (flag == 0.0f) return;              // block-uniform exit

    float4 gb = *reinterpret_cast<const float4*>(gt_bboxes + (size_t)bg * 4);
    int lab = gt_labels[bg];

    u64 dI[KTOP];                          // descending: dI[0] = my max iou key
    u64 dC[KTOP];                          // ascending:  dC[0] = my min cost key
    #pragma unroll
    for (int j = 0; j < KTOP; ++j) { dI[j] = 0ull; dC[j] = ~0ull; }

    for (int n = tid; n < NN; n += 256) {
        float4 pr = *reinterpret_cast<const float4*>(priors + (size_t)n * 4);
        float4 pb = *reinterpret_cast<const float4*>(pred_bboxes + ((size_t)b * NN + n) * 4);
        float lg = pred_scores[((size_t)b * NN + n) * CC + lab];
        float cost, piou;
        pair_cost_iou(pr.x, pr.y, pr.z, pb.x, pb.y, pb.z, pb.w,
                      gb.x, gb.y, gb.z, gb.w, lg, flag, cost, piou);
        s_iou[n] = piou;
        u64 ki = ((u64)f2u(piou) << 32) | (unsigned)n;
        if (ki > dI[KTOP - 1]) {
            dI[KTOP - 1] = ki;
            #pragma unroll
            for (int j = KTOP - 1; j > 0; --j)
                if (dI[j] > dI[j - 1]) { u64 t = dI[j - 1]; dI[j - 1] = dI[j]; dI[j] = t; }
        }
        u64 kc = ((u64)f2u(cost) << 32) | (unsigned)n;
        if (kc < dC[KTOP - 1]) {
            dC[KTOP - 1] = kc;
            #pragma unroll
            for (int j = KTOP - 1; j > 0; --j)
                if (dC[j] < dC[j - 1]) { u64 t = dC[j - 1]; dC[j - 1] = dC[j]; dC[j] = t; }
        }
    }

    // Phase 2: top-13 iou values, summed in descending order (matches top_k().sum(-1))
    float ksum = 0.0f;
    for (int it = 0; it < KTOP; ++it) {
        u64 m = block_max_u64(dI[0], s_red, tid);
        ksum += u2f((unsigned)(m >> 32));
        if (dI[0] == m) {                  // unique winner (key contains n)
            #pragma unroll
            for (int j = 0; j < KTOP - 1; ++j) dI[j] = dI[j + 1];
            dI[KTOP - 1] = 0ull;
        }
    }
    int dyn_k = (int)ksum;                 // trunc toward zero; ksum in [0,13]
    if (dyn_k < 1) dyn_k = 1;

    // Phase 3: dyn_k smallest (cost, idx) — stable-argsort rank semantics
    for (int it = 0; it < dyn_k; ++it) {
        u64 m = block_min_u64(dC[0], s_red, tid);
        if (tid == 0) s_win[it] = (int)(m & 0xffffffffu);
        if (dC[0] == m) {
            #pragma unroll
            for (int j = 0; j < KTOP - 1; ++j) dC[j] = dC[j + 1];
            dC[KTOP - 1] = ~0ull;
        }
    }
    __syncthreads();                       // s_win / s_iou ready

    if (tid < dyn_k) {
        int bi = s_win[tid];
        int idx = b * NN + bi;
        atomicAdd(&match_count[idx], 1);
        match_g[idx]   = g;                // valid only when count==1 (single writer)
        match_iou[idx] = s_iou[bi];
    }
}

// K2a: resolve cnt<=1 priors; compact cnt>1 priors into a list for K2b.
__global__ __launch_bounds__(256) void k2a_resolve(
    const int*   __restrict__ gt_labels,
    const float* __restrict__ gt_bboxes,
    const int*   __restrict__ match_count,
    const int*   __restrict__ match_g,
    const float* __restrict__ match_iou,
    int*   __restrict__ r_lab,
    float* __restrict__ r_miou,
    int*   __restrict__ class_num,
    int*   __restrict__ multi_count,
    int*   __restrict__ multi_list,
    float* __restrict__ out)
{
    int i = blockIdx.x * 256 + threadIdx.x;
    if (i >= BB * NN) return;
    int cnt = match_count[i];
    if (cnt > 1) {
        int p = atomicAdd(multi_count, 1);
        multi_list[p] = i;
        return;                            // K2b finishes these priors
    }
    int b = i / NN;
    int lab = CC;
    float miou = 0.0f;
    float4 bb = make_float4(0.0f, 0.0f, 0.0f, 0.0f);
    if (cnt == 1) {
        int g = match_g[i];
        miou = match_iou[i];
        lab = gt_labels[b * GG + g];
        bb = *reinterpret_cast<const float4*>(gt_bboxes + (size_t)(b * GG + g) * 4);
        atomicAdd(&class_num[lab], 1);
    }
    r_lab[i]  = lab;
    r_miou[i] = miou;
    out[kO_LAB + i] = (float)lab;
    out[kO_FG  + i] = (cnt == 1) ? 1.0f : 0.0f;
    out[kO_MET + i] = miou;
    *reinterpret_cast<float4*>(out + kO_BB + (size_t)i * 4) = bb;
}

// K2b: one wave per multi-matched prior; lanes parallel over gts; argmin reduce.
__global__ __launch_bounds__(256) void k2b_multi(
    const float* __restrict__ pred_bboxes,
    const float* __restrict__ pred_scores,
    const float* __restrict__ priors,
    const int*   __restrict__ gt_labels,
    const float* __restrict__ gt_bboxes,
    const float* __restrict__ pad_flag,
    const int*   __restrict__ multi_count,
    const int*   __restrict__ multi_list,
    int*   __restrict__ r_lab,
    float* __restrict__ r_miou,
    int*   __restrict__ class_num,
    float* __restrict__ out)
{
    int wid  = (blockIdx.x * 256 + threadIdx.x) >> 6;
    int lane = threadIdx.x & 63;
    int cnt = *multi_count;
    if (wid >= cnt) return;                // wave-uniform exit
    int i = multi_list[wid];
    int b = i / NN, n = i % NN;

    float4 pr = *reinterpret_cast<const float4*>(priors + (size_t)n * 4);
    float4 pb = *reinterpret_cast<const float4*>(pred_bboxes + (size_t)i * 4);

    u64 bestk = ~0ull;
    float bestiou = 0.0f;
    #pragma unroll
    for (int s = 0; s < 2; ++s) {
        int g = lane + s * 64;
        if (g < GG) {
            float flag = pad_flag[b * GG + g];
            float4 gb = *reinterpret_cast<const float4*>(gt_bboxes + (size_t)(b * GG + g) * 4);
            int lb = gt_labels[b * GG + g];
            float lg = pred_scores[(size_t)i * CC + lb];
            float cost, piou;
            pair_cost_iou(pr.x, pr.y, pr.z, pb.x, pb.y, pb.z, pb.w,
                          gb.x, gb.y, gb.z, gb.w, lg, flag, cost, piou);
            u64 k = ((u64)f2u(cost) << 32) | (unsigned)g;   // tie -> smallest g
            if (k < bestk) { bestk = k; bestiou = piou; }
        }
    }
    #pragma unroll
    for (int off = 32; off > 0; off >>= 1) {
        u64 ok = __shfl_down(bestk, off, 64);
        float op = __shfl_down(bestiou, off, 64);
        if (ok < bestk) { bestk = ok; bestiou = op; }
    }
    if (lane == 0) {
        int g = (int)(bestk & 0xffffffffu);
        int lab = gt_labels[b * GG + g];
        float4 bb = *reinterpret_cast<const float4*>(gt_bboxes + (size_t)(b * GG + g) * 4);
        atomicAdd(&class_num[lab], 1);
        r_lab[i]  = lab;
        r_miou[i] = bestiou;
        out[kO_LAB + i] = (float)lab;
        out[kO_FG  + i] = 1.0f;
        out[kO_MET + i] = bestiou;
        *reinterpret_cast<float4*>(out + kO_BB + (size_t)i * 4) = bb;
    }
}

// K3: class counts -> dynamic weights
__global__ void k3_weights(const int* __restrict__ class_num,
                           float* __restrict__ dynw,
                           float* __restrict__ out)
{
    __shared__ float s_max;
    int c = threadIdx.x;
    if (c == 0) {
        int m = 0;
        for (int i = 0; i < CC; ++i) m = max(m, class_num[i]);
        s_max = (float)m;
    }
    __syncthreads();
    if (c < CC) {
        int num = class_num[c];
        float w = (num > 0) ? s_max / fmaxf((float)num, 1.0f) : 1.0f;
        dynw[c] = w;
        out[kO_NUM  + c] = (float)num;
        out[kO_DYNW + c] = w;
    }
}

// K4: fill assigned_scores and assigned_labels_weights (coalesced over B*N*C)
__global__ __launch_bounds__(256) void k4_fill(
    const int*   __restrict__ r_lab,
    const float* __restrict__ r_miou,
    const float* __restrict__ dynw,
    float* __restrict__ out)
{
    size_t idx = (size_t)blockIdx.x * 256 + threadIdx.x;
    if (idx >= (size_t)BB * NN * CC) return;
    int i = (int)(idx / CC);
    int c = (int)(idx % CC);
    int lab = r_lab[i];
    bool fg = (lab < CC);
    float miou = r_miou[i];
    out[kO_SC + idx] = (lab == c) ? miou : 0.0f;   // lab==c implies fg
    out[kO_W  + idx] = fg ? dynw[c] : 1.0f;
}

// K5: area_dist (3, B, G)
__global__ void k5_area(const float* __restrict__ gt_area,
                        const float* __restrict__ area_rule,
                        const float* __restrict__ pad_flag,
                        float* __restrict__ out)
{
    int idx = blockIdx.x * 256 + threadIdx.x;
    if (idx >= 3 * BB * GG) return;
    int z = idx / (BB * GG);
    int rem = idx % (BB * GG);
    float ga = gt_area[rem];
    float lo = area_rule[z] * area_rule[z];
    float hi = area_rule[z + 1] * area_rule[z + 1];
    bool v = (ga >= lo) && (ga < hi) && (pad_flag[rem] > 0.0f);
    out[kO_AREA + idx] = v ? 1.0f : 0.0f;
}

extern "C" void kernel_launch(void* const* d_in, const int* in_sizes, int n_in,
                              void* d_out, int out_size, void* d_ws, size_t ws_size,
                              hipStream_t stream)
{
    const float* pred_bboxes = (const float*)d_in[0];
    const float* pred_scores = (const float*)d_in[1];
    const float* priors      = (const float*)d_in[2];
    const int*   gt_labels   = (const int*)d_in[3];
    const float* gt_bboxes   = (const float*)d_in[4];
    const float* pad_flag    = (const float*)d_in[5];
    const float* gt_area     = (const float*)d_in[6];
    const float* area_rule   = (const float*)d_in[7];
    float* out = (float*)d_out;

    // workspace layout: [match_count BB*NN][class_num CC][multi_count 1] zeroed together
    char* w = (char*)d_ws;
    int*   match_count = (int*)w;   w += (size_t)BB * NN * 4;
    int*   class_num   = (int*)w;   w += (size_t)CC * 4;
    int*   multi_count = (int*)w;   w += 4;
    int*   multi_list  = (int*)w;   w += (size_t)MAXMULTI * 4;
    int*   match_g     = (int*)w;   w += (size_t)BB * NN * 4;
    float* match_iou   = (float*)w; w += (size_t)BB * NN * 4;
    int*   r_lab       = (int*)w;   w += (size_t)BB * NN * 4;
    float* r_miou      = (float*)w; w += (size_t)BB * NN * 4;
    float* dynw        = (float*)w; w += (size_t)CC * 4;

    hipMemsetAsync(d_ws, 0, (size_t)(BB * NN + CC + 1) * 4, stream);

    k1_match<<<BB * GG, 256, 0, stream>>>(
        pred_bboxes, pred_scores, priors, gt_labels, gt_bboxes, pad_flag,
        match_count, match_g, match_iou);

    k2a_resolve<<<(BB * NN + 255) / 256, 256, 0, stream>>>(
        gt_labels, gt_bboxes, match_count, match_g, match_iou,
        r_lab, r_miou, class_num, multi_count, multi_list, out);

    k2b_multi<<<(MAXMULTI / 4 + 0), 256, 0, stream>>>(
        pred_bboxes, pred_scores, priors, gt_labels, gt_bboxes, pad_flag,
        multi_count, multi_list, r_lab, r_miou, class_num, out);

    k3_weights<<<1, 128, 0, stream>>>(class_num, dynw, out);

    k4_fill<<<(int)(((size_t)BB * NN * CC + 255) / 256), 256, 0, stream>>>(
        r_lab, r_miou, dynw, out);

    k5_area<<<(3 * BB * GG + 255) / 256, 256, 0, stream>>>(
        gt_area, area_rule, pad_flag, out);
}

// Round 3
// 240.084 us; speedup vs baseline: 4.3095x; 1.4733x over previous
//
#include <hip/hip_runtime.h>

typedef unsigned long long u64;

#define BB 16
#define NN 8400
#define GG 100
#define CC 80
#define KTOP 13
#define EPSF 1e-7f
#define INFC 1e8f
#define MAXIN 1024                      // max inside priors per gt (max box 144^2 -> ~425 expected)
#define MAXMULTI (BB * GG * KTOP / 2)

static constexpr size_t kO_LAB  = 0;
static constexpr size_t kO_W    = (size_t)BB * NN;               // 134400
static constexpr size_t kO_BB   = kO_W + (size_t)BB * NN * CC;   // 10886400
static constexpr size_t kO_SC   = kO_BB + (size_t)BB * NN * 4;   // 11424000
static constexpr size_t kO_MET  = kO_SC + (size_t)BB * NN * CC;  // 22176000
static constexpr size_t kO_FG   = kO_MET + (size_t)BB * NN;      // 22310400
static constexpr size_t kO_NUM  = kO_FG + (size_t)BB * NN;       // 22444800
static constexpr size_t kO_DYNW = kO_NUM + CC;                   // 22444880
static constexpr size_t kO_AREA = kO_DYNW + CC;                  // 22444960

// monotone float->uint mapping (total order matching float <)
__device__ __forceinline__ unsigned f2u(float x) {
    unsigned b = __float_as_uint(x);
    return (b & 0x80000000u) ? ~b : (b | 0x80000000u);
}
__device__ __forceinline__ float u2f(unsigned e) {
    return __uint_as_float((e & 0x80000000u) ? (e & 0x7fffffffu) : ~e);
}

// Full pair cost + piou for an INSIDE prior (is_in == flag > 0).
// Bit-identical to the previously passing version's inside path.
__device__ __forceinline__ void pair_cost_iou_inside(
    float px, float py, float st,
    float p0, float p1, float p2, float p3,
    float g0, float g1, float g2, float g3,
    float lg, float flag,
    float& cost, float& piou)
{
    float gcx = (g0 + g2) * 0.5f, gcy = (g1 + g3) * 0.5f;
    float dx = px - gcx, dy = py - gcy;
    float dist = sqrtf(dx * dx + dy * dy) / st * flag;
    float scp = exp2f((dist - 3.0f) * 3.32192809488736f) * flag;
    float ix1 = fmaxf(p0, g0), iy1 = fmaxf(p1, g1);
    float ix2 = fminf(p2, g2), iy2 = fminf(p3, g3);
    float ow = fmaxf(ix2 - ix1, 0.0f), oh = fmaxf(iy2 - iy1, 0.0f);
    float ov = ow * oh;
    float a1 = (p2 - p0) * (p3 - p1);
    float a2 = (g2 - g0) * (g3 - g1);
    float uni = fmaxf(a1 + a2 - ov, EPSF);
    float iou = ov / uni;
    float ex1 = fminf(p0, g0), ey1 = fminf(p1, g1);
    float ex2 = fmaxf(p2, g2), ey2 = fmaxf(p3, g3);
    float ew = fmaxf(ex2 - ex1, 0.0f), eh = fmaxf(ey2 - ey1, 0.0f);
    float enc = fmaxf(ew * eh, EPSF);
    float giou = iou - (enc - uni) / enc;
    piou = fabsf(giou * flag);
    float iou_cost = -__logf(piou + EPSF) * 3.0f;
    float sig = 1.0f / (1.0f + __expf(-lg));
    float sc = piou - sig;
    float asc = fabsf(sc);
    float bce = fmaxf(lg, 0.0f) - lg * piou + log1pf(__expf(-fabsf(lg)));
    float cls = bce * __expf(asc - 1.0f) * asc;
    cost = cls + iou_cost + scp;
}

// Full pair (any prior) — used by K2b multi-resolve.
__device__ __forceinline__ void pair_cost_iou(
    float px, float py, float st,
    float p0, float p1, float p2, float p3,
    float g0, float g1, float g2, float g3,
    float lg, float flag,
    float& cost, float& piou)
{
    float l = px - g0, t = py - g1, r = g2 - px, d = g3 - py;
    float mn = fminf(fminf(l, t), fminf(r, d));
    float is_in = (mn > 0.0f) ? flag : 0.0f;
    float gcx = (g0 + g2) * 0.5f, gcy = (g1 + g3) * 0.5f;
    float dx = px - gcx, dy = py - gcy;
    float dist = sqrtf(dx * dx + dy * dy) / st * is_in;
    float scp = exp2f((dist - 3.0f) * 3.32192809488736f) * is_in;
    float ix1 = fmaxf(p0, g0), iy1 = fmaxf(p1, g1);
    float ix2 = fminf(p2, g2), iy2 = fminf(p3, g3);
    float ow = fmaxf(ix2 - ix1, 0.0f), oh = fmaxf(iy2 - iy1, 0.0f);
    float ov = ow * oh;
    float a1 = (p2 - p0) * (p3 - p1);
    float a2 = (g2 - g0) * (g3 - g1);
    float uni = fmaxf(a1 + a2 - ov, EPSF);
    float iou = ov / uni;
    float ex1 = fminf(p0, g0), ey1 = fminf(p1, g1);
    float ex2 = fmaxf(p2, g2), ey2 = fmaxf(p3, g3);
    float ew = fmaxf(ex2 - ex1, 0.0f), eh = fmaxf(ey2 - ey1, 0.0f);
    float enc = fmaxf(ew * eh, EPSF);
    float giou = iou - (enc - uni) / enc;
    piou = fabsf(giou * is_in);
    float iou_cost = -__logf(piou + EPSF) * 3.0f;
    float sig = 1.0f / (1.0f + __expf(-lg));
    float sc = piou - sig;
    float asc = fabsf(sc);
    float bce = fmaxf(lg, 0.0f) - lg * piou + log1pf(__expf(-fabsf(lg)));
    float cls = bce * __expf(asc - 1.0f) * asc;
    float cc = cls + iou_cost + scp;
    cost = (is_in > 0.0f) ? cc : INFC;
}

__device__ __forceinline__ u64 block_max_u64(u64 v, u64* s_red, int tid) {
    #pragma unroll
    for (int off = 32; off > 0; off >>= 1) {
        u64 o = __shfl_down(v, off, 64);
        if (o > v) v = o;
    }
    __syncthreads();                       // protect s_red WAR from prev round
    if ((tid & 63) == 0) s_red[tid >> 6] = v;
    __syncthreads();
    u64 m = s_red[0];
    #pragma unroll
    for (int i = 1; i < 4; ++i) if (s_red[i] > m) m = s_red[i];
    return m;
}
__device__ __forceinline__ u64 block_min_u64(u64 v, u64* s_red, int tid) {
    #pragma unroll
    for (int off = 32; off > 0; off >>= 1) {
        u64 o = __shfl_down(v, off, 64);
        if (o < v) v = o;
    }
    __syncthreads();
    if ((tid & 63) == 0) s_red[tid >> 6] = v;
    __syncthreads();
    u64 m = s_red[0];
    #pragma unroll
    for (int i = 1; i < 4; ++i) if (s_red[i] < m) m = s_red[i];
    return m;
}

// K1: one workgroup per (b,g). Pass1: cheap inside-test + compaction.
// Pass2: full cost only on compacted set. Selection over register mini-lists.
__global__ __launch_bounds__(256) void k1_match(
    const float* __restrict__ pred_bboxes,
    const float* __restrict__ pred_scores,
    const float* __restrict__ priors,
    const int*   __restrict__ gt_labels,
    const float* __restrict__ gt_bboxes,
    const float* __restrict__ pad_flag,
    int*   __restrict__ match_count,
    int*   __restrict__ match_g,
    float* __restrict__ match_iou)
{
    __shared__ int s_cnt;
    __shared__ int s_list[MAXIN];
    __shared__ u64 s_red[4];

    int bg = blockIdx.x;
    int b = bg / GG, g = bg - b * GG;
    int tid = threadIdx.x;

    float flag = pad_flag[bg];
    if (flag == 0.0f) return;              // block-uniform exit

    if (tid == 0) s_cnt = 0;
    __syncthreads();

    float4 gb = *reinterpret_cast<const float4*>(gt_bboxes + (size_t)bg * 4);

    // Pass 1: inside test + LDS compaction (only ~1.6% of priors are inside)
    for (int n = tid; n < NN; n += 256) {
        float2 p = *reinterpret_cast<const float2*>(priors + (size_t)n * 4);
        float l = p.x - gb.x, t = p.y - gb.y;
        float r = gb.z - p.x, d = gb.w - p.y;
        float mn = fminf(fminf(l, t), fminf(r, d));
        if (mn > 0.0f) {
            int po = atomicAdd(&s_cnt, 1);
            if (po < MAXIN) s_list[po] = n;
        }
    }
    __syncthreads();
    int M = min(s_cnt, MAXIN);

    if (M == 0) {
        // no inside priors: dyn_k = 1, all costs INFC -> stable-rank winner is prior 0
        if (tid == 0) {
            int idx = b * NN;
            atomicAdd(&match_count[idx], 1);
            match_g[idx]   = g;
            match_iou[idx] = 0.0f;
        }
        return;
    }

    int lab = gt_labels[bg];

    // register mini-lists (capacity 4 = max candidates/thread at M<=1024)
    u64 zs = ((u64)0x80000000u << 32) | (0x10000u + (unsigned)tid * 4u); // iou 0.0, unique
    u64 iK0 = zs, iK1 = zs + 1, iK2 = zs + 2, iK3 = zs + 3;  // descending iou keys
    u64 cK0 = ~0ull, cK1 = ~0ull, cK2 = ~0ull, cK3 = ~0ull;  // ascending cost keys
    float cP0 = 0.f, cP1 = 0.f, cP2 = 0.f, cP3 = 0.f;        // piou paired with cK

    for (int m = tid; m < M; m += 256) {
        int n = s_list[m];
        float4 pr = *reinterpret_cast<const float4*>(priors + (size_t)n * 4);
        float4 pb = *reinterpret_cast<const float4*>(pred_bboxes + ((size_t)b * NN + n) * 4);
        float lg = pred_scores[((size_t)b * NN + n) * CC + lab];
        float cost, piou;
        pair_cost_iou_inside(pr.x, pr.y, pr.z, pb.x, pb.y, pb.z, pb.w,
                             gb.x, gb.y, gb.z, gb.w, lg, flag, cost, piou);
        u64 ki = ((u64)f2u(piou) << 32) | (unsigned)n;
        if (ki > iK3) {
            iK3 = ki;
            if (iK3 > iK2) { u64 t0 = iK2; iK2 = iK3; iK3 = t0; }
            if (iK2 > iK1) { u64 t0 = iK1; iK1 = iK2; iK2 = t0; }
            if (iK1 > iK0) { u64 t0 = iK0; iK0 = iK1; iK1 = t0; }
        }
        u64 kc = ((u64)f2u(cost) << 32) | (unsigned)n;
        if (kc < cK3) {
            cK3 = kc; cP3 = piou;
            if (cK3 < cK2) { u64 t0 = cK2; cK2 = cK3; cK3 = t0; float f0 = cP2; cP2 = cP3; cP3 = f0; }
            if (cK2 < cK1) { u64 t0 = cK1; cK1 = cK2; cK2 = t0; float f0 = cP1; cP1 = cP2; cP2 = f0; }
            if (cK1 < cK0) { u64 t0 = cK0; cK0 = cK1; cK1 = t0; float f0 = cP0; cP0 = cP1; cP1 = f0; }
        }
    }

    // top-13 iou values, summed descending (matches top_k().sum(-1)); zeros pad
    float ksum = 0.0f;
    for (int it = 0; it < KTOP; ++it) {
        u64 mx = block_max_u64(iK0, s_red, tid);
        ksum += u2f((unsigned)(mx >> 32));
        if (iK0 == mx) { iK0 = iK1; iK1 = iK2; iK2 = iK3; iK3 = 0ull; }
    }
    int dyn_k = (int)ksum;                 // trunc; dyn_k <= M guaranteed (|giou|<=1)
    if (dyn_k < 1) dyn_k = 1;

    // dyn_k smallest (cost, n) — stable-argsort rank semantics; popper scatters
    for (int it = 0; it < dyn_k; ++it) {
        u64 mn = block_min_u64(cK0, s_red, tid);
        if (cK0 == mn) {
            int bi = (int)(mn & 0xffffffffu);
            int idx = b * NN + bi;
            atomicAdd(&match_count[idx], 1);
            match_g[idx]   = g;            // valid only when final count==1
            match_iou[idx] = cP0;
            cK0 = cK1; cP0 = cP1; cK1 = cK2; cP1 = cP2; cK2 = cK3; cP2 = cP3;
            cK3 = ~0ull;
        }
    }
}

// K2a: resolve cnt<=1 priors; compact cnt>1 priors into a list for K2b.
__global__ __launch_bounds__(256) void k2a_resolve(
    const int*   __restrict__ gt_labels,
    const float* __restrict__ gt_bboxes,
    const int*   __restrict__ match_count,
    const int*   __restrict__ match_g,
    const float* __restrict__ match_iou,
    int*   __restrict__ r_lab,
    float* __restrict__ r_miou,
    int*   __restrict__ class_num,
    int*   __restrict__ multi_count,
    int*   __restrict__ multi_list,
    float* __restrict__ out)
{
    int i = blockIdx.x * 256 + threadIdx.x;
    if (i >= BB * NN) return;
    int cnt = match_count[i];
    if (cnt > 1) {
        int p = atomicAdd(multi_count, 1);
        multi_list[p] = i;
        return;                            // K2b finishes these priors
    }
    int b = i / NN;
    int lab = CC;
    float miou = 0.0f;
    float4 bb = make_float4(0.0f, 0.0f, 0.0f, 0.0f);
    if (cnt == 1) {
        int g = match_g[i];
        miou = match_iou[i];
        lab = gt_labels[b * GG + g];
        bb = *reinterpret_cast<const float4*>(gt_bboxes + (size_t)(b * GG + g) * 4);
        atomicAdd(&class_num[lab], 1);
    }
    r_lab[i]  = lab;
    r_miou[i] = miou;
    out[kO_LAB + i] = (float)lab;
    out[kO_FG  + i] = (cnt == 1) ? 1.0f : 0.0f;
    out[kO_MET + i] = miou;
    *reinterpret_cast<float4*>(out + kO_BB + (size_t)i * 4) = bb;
}

// K2b: one wave per multi-matched prior; lanes parallel over gts; argmin reduce.
__global__ __launch_bounds__(256) void k2b_multi(
    const float* __restrict__ pred_bboxes,
    const float* __restrict__ pred_scores,
    const float* __restrict__ priors,
    const int*   __restrict__ gt_labels,
    const float* __restrict__ gt_bboxes,
    const float* __restrict__ pad_flag,
    const int*   __restrict__ multi_count,
    const int*   __restrict__ multi_list,
    int*   __restrict__ r_lab,
    float* __restrict__ r_miou,
    int*   __restrict__ class_num,
    float* __restrict__ out)
{
    int wid  = (blockIdx.x * 256 + threadIdx.x) >> 6;
    int lane = threadIdx.x & 63;
    int cnt = *multi_count;
    if (wid >= cnt) return;                // wave-uniform exit
    int i = multi_list[wid];
    int b = i / NN, n = i - b * NN;

    float4 pr = *reinterpret_cast<const float4*>(priors + (size_t)n * 4);
    float4 pb = *reinterpret_cast<const float4*>(pred_bboxes + (size_t)i * 4);

    u64 bestk = ~0ull;
    float bestiou = 0.0f;
    #pragma unroll
    for (int s = 0; s < 2; ++s) {
        int g = lane + s * 64;
        if (g < GG) {
            float flag = pad_flag[b * GG + g];
            float4 gb = *reinterpret_cast<const float4*>(gt_bboxes + (size_t)(b * GG + g) * 4);
            int lb = gt_labels[b * GG + g];
            float lg = pred_scores[(size_t)i * CC + lb];
            float cost, piou;
            pair_cost_iou(pr.x, pr.y, pr.z, pb.x, pb.y, pb.z, pb.w,
                          gb.x, gb.y, gb.z, gb.w, lg, flag, cost, piou);
            u64 k = ((u64)f2u(cost) << 32) | (unsigned)g;   // tie -> smallest g
            if (k < bestk) { bestk = k; bestiou = piou; }
        }
    }
    #pragma unroll
    for (int off = 32; off > 0; off >>= 1) {
        u64 ok = __shfl_down(bestk, off, 64);
        float op = __shfl_down(bestiou, off, 64);
        if (ok < bestk) { bestk = ok; bestiou = op; }
    }
    if (lane == 0) {
        int g = (int)(bestk & 0xffffffffu);
        int lab = gt_labels[b * GG + g];
        float4 bb = *reinterpret_cast<const float4*>(gt_bboxes + (size_t)(b * GG + g) * 4);
        atomicAdd(&class_num[lab], 1);
        r_lab[i]  = lab;
        r_miou[i] = bestiou;
        out[kO_LAB + i] = (float)lab;
        out[kO_FG  + i] = 1.0f;
        out[kO_MET + i] = bestiou;
        *reinterpret_cast<float4*>(out + kO_BB + (size_t)i * 4) = bb;
    }
}

// K3: class counts -> dynamic weights (one wave)
__global__ void k3_weights(const int* __restrict__ class_num,
                           float* __restrict__ dynw,
                           float* __restrict__ out)
{
    int lane = threadIdx.x;                // 64 threads
    int n0 = class_num[lane];
    int n1 = (lane < CC - 64) ? class_num[lane + 64] : 0;
    int m = max(n0, n1);
    #pragma unroll
    for (int off = 32; off > 0; off >>= 1) m = max(m, __shfl_down(m, off, 64));
    m = __shfl(m, 0, 64);
    float fm = (float)m;
    {
        float w = (n0 > 0) ? fm / fmaxf((float)n0, 1.0f) : 1.0f;
        dynw[lane] = w;
        out[kO_NUM  + lane] = (float)n0;
        out[kO_DYNW + lane] = w;
    }
    if (lane < CC - 64) {
        float w = (n1 > 0) ? fm / fmaxf((float)n1, 1.0f) : 1.0f;
        dynw[lane + 64] = w;
        out[kO_NUM  + lane + 64] = (float)n1;
        out[kO_DYNW + lane + 64] = w;
    }
}

// K4: fill assigned_scores + weights; float4 stores, u32 index math.
// grid = BB*NN*(CC/4)/256 = 10500 blocks exactly.
__global__ __launch_bounds__(256) void k4_fill(
    const int*   __restrict__ r_lab,
    const float* __restrict__ r_miou,
    const float* __restrict__ dynw,
    float* __restrict__ out)
{
    __shared__ float s_w[CC];
    if (threadIdx.x < CC) s_w[threadIdx.x] = dynw[threadIdx.x];
    __syncthreads();
    unsigned t = blockIdx.x * 256u + threadIdx.x;   // < 2,688,000
    unsigned i = t / 20u;                            // const-div -> mulhi
    unsigned cq = (t - i * 20u) * 4u;
    int lab = r_lab[i];
    float miou = r_miou[i];
    bool fg = lab < CC;
    unsigned ulab = (unsigned)lab;
    float4 sc, wv;
    sc.x = (ulab == cq + 0u) ? miou : 0.0f;
    sc.y = (ulab == cq + 1u) ? miou : 0.0f;
    sc.z = (ulab == cq + 2u) ? miou : 0.0f;
    sc.w = (ulab == cq + 3u) ? miou : 0.0f;
    wv.x = fg ? s_w[cq + 0u] : 1.0f;
    wv.y = fg ? s_w[cq + 1u] : 1.0f;
    wv.z = fg ? s_w[cq + 2u] : 1.0f;
    wv.w = fg ? s_w[cq + 3u] : 1.0f;
    size_t base = (size_t)i * CC + cq;
    *reinterpret_cast<float4*>(out + kO_SC + base) = sc;
    *reinterpret_cast<float4*>(out + kO_W  + base) = wv;
}

// K5: area_dist (3, B, G)
__global__ void k5_area(const float* __restrict__ gt_area,
                        const float* __restrict__ area_rule,
                        const float* __restrict__ pad_flag,
                        float* __restrict__ out)
{
    int idx = blockIdx.x * 256 + threadIdx.x;
    if (idx >= 3 * BB * GG) return;
    int z = idx / (BB * GG);
    int rem = idx - z * (BB * GG);
    float ga = gt_area[rem];
    float lo = area_rule[z] * area_rule[z];
    float hi = area_rule[z + 1] * area_rule[z + 1];
    bool v = (ga >= lo) && (ga < hi) && (pad_flag[rem] > 0.0f);
    out[kO_AREA + idx] = v ? 1.0f : 0.0f;
}

extern "C" void kernel_launch(void* const* d_in, const int* in_sizes, int n_in,
                              void* d_out, int out_size, void* d_ws, size_t ws_size,
                              hipStream_t stream)
{
    const float* pred_bboxes = (const float*)d_in[0];
    const float* pred_scores = (const float*)d_in[1];
    const float* priors      = (const float*)d_in[2];
    const int*   gt_labels   = (const int*)d_in[3];
    const float* gt_bboxes   = (const float*)d_in[4];
    const float* pad_flag    = (const float*)d_in[5];
    const float* gt_area     = (const float*)d_in[6];
    const float* area_rule   = (const float*)d_in[7];
    float* out = (float*)d_out;

    // workspace layout: [match_count BB*NN][class_num CC][multi_count 1] zeroed together
    char* w = (char*)d_ws;
    int*   match_count = (int*)w;   w += (size_t)BB * NN * 4;
    int*   class_num   = (int*)w;   w += (size_t)CC * 4;
    int*   multi_count = (int*)w;   w += 4;
    int*   multi_list  = (int*)w;   w += (size_t)MAXMULTI * 4;
    int*   match_g     = (int*)w;   w += (size_t)BB * NN * 4;
    float* match_iou   = (float*)w; w += (size_t)BB * NN * 4;
    int*   r_lab       = (int*)w;   w += (size_t)BB * NN * 4;
    float* r_miou      = (float*)w; w += (size_t)BB * NN * 4;
    float* dynw        = (float*)w; w += (size_t)CC * 4;

    hipMemsetAsync(d_ws, 0, (size_t)(BB * NN + CC + 1) * 4, stream);

    k1_match<<<BB * GG, 256, 0, stream>>>(
        pred_bboxes, pred_scores, priors, gt_labels, gt_bboxes, pad_flag,
        match_count, match_g, match_iou);

    k2a_resolve<<<(BB * NN + 255) / 256, 256, 0, stream>>>(
        gt_labels, gt_bboxes, match_count, match_g, match_iou,
        r_lab, r_miou, class_num, multi_count, multi_list, out);

    k2b_multi<<<(MAXMULTI * 64 + 255) / 256, 256, 0, stream>>>(
        pred_bboxes, pred_scores, priors, gt_labels, gt_bboxes, pad_flag,
        multi_count, multi_list, r_lab, r_miou, class_num, out);

    k3_weights<<<1, 64, 0, stream>>>(class_num, dynw, out);

    k4_fill<<<(int)(((size_t)BB * NN * (CC / 4) + 255) / 256), 256, 0, stream>>>(
        r_lab, r_miou, dynw, out);

    k5_area<<<(3 * BB * GG + 255) / 256, 256, 0, stream>>>(
        gt_area, area_rule, pad_flag, out);
}

// Round 4
// 232.161 us; speedup vs baseline: 4.4566x; 1.0341x over previous
//
#include <hip/hip_runtime.h>

typedef unsigned long long u64;

#define BB 16
#define NN 8400
#define GG 100
#define CC 80
#define KTOP 13
#define EPSF 1e-7f
#define INFC 1e8f
#define MAXIN 1024                      // max inside priors per gt (real max ~500)

static constexpr size_t kO_LAB  = 0;
static constexpr size_t kO_W    = (size_t)BB * NN;               // 134400
static constexpr size_t kO_BB   = kO_W + (size_t)BB * NN * CC;   // 10886400
static constexpr size_t kO_SC   = kO_BB + (size_t)BB * NN * 4;   // 11424000
static constexpr size_t kO_MET  = kO_SC + (size_t)BB * NN * CC;  // 22176000
static constexpr size_t kO_FG   = kO_MET + (size_t)BB * NN;      // 22310400
static constexpr size_t kO_NUM  = kO_FG + (size_t)BB * NN;       // 22444800
static constexpr size_t kO_DYNW = kO_NUM + CC;                   // 22444880
static constexpr size_t kO_AREA = kO_DYNW + CC;                  // 22444960

// monotone float->uint mapping (total order matching float <)
__device__ __forceinline__ unsigned f2u(float x) {
    unsigned b = __float_as_uint(x);
    return (b & 0x80000000u) ? ~b : (b | 0x80000000u);
}
__device__ __forceinline__ float u2f(unsigned e) {
    return __uint_as_float((e & 0x80000000u) ? (e & 0x7fffffffu) : ~e);
}

// Full pair cost + piou for an INSIDE prior (is_in == flag > 0).
__device__ __forceinline__ void pair_cost_iou_inside(
    float px, float py, float st,
    float p0, float p1, float p2, float p3,
    float g0, float g1, float g2, float g3,
    float lg, float flag,
    float& cost, float& piou)
{
    float gcx = (g0 + g2) * 0.5f, gcy = (g1 + g3) * 0.5f;
    float dx = px - gcx, dy = py - gcy;
    float dist = sqrtf(dx * dx + dy * dy) / st * flag;
    float scp = exp2f((dist - 3.0f) * 3.32192809488736f) * flag;
    float ix1 = fmaxf(p0, g0), iy1 = fmaxf(p1, g1);
    float ix2 = fminf(p2, g2), iy2 = fminf(p3, g3);
    float ow = fmaxf(ix2 - ix1, 0.0f), oh = fmaxf(iy2 - iy1, 0.0f);
    float ov = ow * oh;
    float a1 = (p2 - p0) * (p3 - p1);
    float a2 = (g2 - g0) * (g3 - g1);
    float uni = fmaxf(a1 + a2 - ov, EPSF);
    float iou = ov / uni;
    float ex1 = fminf(p0, g0), ey1 = fminf(p1, g1);
    float ex2 = fmaxf(p2, g2), ey2 = fmaxf(p3, g3);
    float ew = fmaxf(ex2 - ex1, 0.0f), eh = fmaxf(ey2 - ey1, 0.0f);
    float enc = fmaxf(ew * eh, EPSF);
    float giou = iou - (enc - uni) / enc;
    piou = fabsf(giou * flag);
    float iou_cost = -__logf(piou + EPSF) * 3.0f;
    float sig = 1.0f / (1.0f + __expf(-lg));
    float sc = piou - sig;
    float asc = fabsf(sc);
    float bce = fmaxf(lg, 0.0f) - lg * piou + log1pf(__expf(-fabsf(lg)));
    float cls = bce * __expf(asc - 1.0f) * asc;
    cost = cls + iou_cost + scp;
}

// Full pair (any prior) — used by the fused multi-resolve in K2.
__device__ __forceinline__ void pair_cost_iou(
    float px, float py, float st,
    float p0, float p1, float p2, float p3,
    float g0, float g1, float g2, float g3,
    float lg, float flag,
    float& cost, float& piou)
{
    float l = px - g0, t = py - g1, r = g2 - px, d = g3 - py;
    float mn = fminf(fminf(l, t), fminf(r, d));
    float is_in = (mn > 0.0f) ? flag : 0.0f;
    float gcx = (g0 + g2) * 0.5f, gcy = (g1 + g3) * 0.5f;
    float dx = px - gcx, dy = py - gcy;
    float dist = sqrtf(dx * dx + dy * dy) / st * is_in;
    float scp = exp2f((dist - 3.0f) * 3.32192809488736f) * is_in;
    float ix1 = fmaxf(p0, g0), iy1 = fmaxf(p1, g1);
    float ix2 = fminf(p2, g2), iy2 = fminf(p3, g3);
    float ow = fmaxf(ix2 - ix1, 0.0f), oh = fmaxf(iy2 - iy1, 0.0f);
    float ov = ow * oh;
    float a1 = (p2 - p0) * (p3 - p1);
    float a2 = (g2 - g0) * (g3 - g1);
    float uni = fmaxf(a1 + a2 - ov, EPSF);
    float iou = ov / uni;
    float ex1 = fminf(p0, g0), ey1 = fminf(p1, g1);
    float ex2 = fmaxf(p2, g2), ey2 = fmaxf(p3, g3);
    float ew = fmaxf(ex2 - ex1, 0.0f), eh = fmaxf(ey2 - ey1, 0.0f);
    float enc = fmaxf(ew * eh, EPSF);
    float giou = iou - (enc - uni) / enc;
    piou = fabsf(giou * is_in);
    float iou_cost = -__logf(piou + EPSF) * 3.0f;
    float sig = 1.0f / (1.0f + __expf(-lg));
    float sc = piou - sig;
    float asc = fabsf(sc);
    float bce = fmaxf(lg, 0.0f) - lg * piou + log1pf(__expf(-fabsf(lg)));
    float cls = bce * __expf(asc - 1.0f) * asc;
    float cc = cls + iou_cost + scp;
    cost = (is_in > 0.0f) ? cc : INFC;
}

// K1: one workgroup per (b,g). Pass1 inside-test+compaction; pass2 full cost on
// compacted set; selection = wave-local shuffle merges + single-wave final merge.
// Barriers: 4 total (was ~48).
__global__ __launch_bounds__(256) void k1_match(
    const float* __restrict__ pred_bboxes,
    const float* __restrict__ pred_scores,
    const float* __restrict__ priors,
    const int*   __restrict__ gt_labels,
    const float* __restrict__ gt_bboxes,
    const float* __restrict__ pad_flag,
    int*   __restrict__ match_count,
    int*   __restrict__ match_g,
    float* __restrict__ match_iou)
{
    __shared__ int   s_cnt;
    __shared__ int   s_list[MAXIN];
    __shared__ u64   s_cand[4 * KTOP];
    __shared__ float s_candP[4 * KTOP];
    __shared__ int   s_dynk;

    int bg = blockIdx.x;
    int b = bg / GG, g = bg - b * GG;
    int tid  = threadIdx.x;
    int lane = tid & 63;
    int w    = tid >> 6;

    float flag = pad_flag[bg];
    if (flag == 0.0f) return;              // block-uniform exit

    if (tid == 0) s_cnt = 0;
    __syncthreads();

    float4 gb = *reinterpret_cast<const float4*>(gt_bboxes + (size_t)bg * 4);

    // Pass 1: inside test + LDS compaction. 8400 = 32*256 + 208.
    #pragma unroll 4
    for (int k = 0; k < 32; ++k) {
        int n = tid + (k << 8);
        float4 p = *reinterpret_cast<const float4*>(priors + (size_t)n * 4);
        float mn = fminf(fminf(p.x - gb.x, p.y - gb.y),
                         fminf(gb.z - p.x, gb.w - p.y));
        if (mn > 0.0f) {
            int po = atomicAdd(&s_cnt, 1);
            if (po < MAXIN) s_list[po] = n;
        }
    }
    if (tid < NN - 8192) {
        int n = tid + 8192;
        float4 p = *reinterpret_cast<const float4*>(priors + (size_t)n * 4);
        float mn = fminf(fminf(p.x - gb.x, p.y - gb.y),
                         fminf(gb.z - p.x, gb.w - p.y));
        if (mn > 0.0f) {
            int po = atomicAdd(&s_cnt, 1);
            if (po < MAXIN) s_list[po] = n;
        }
    }
    __syncthreads();
    int M = min(s_cnt, MAXIN);

    if (M == 0) {
        // all costs INFC -> stable-rank winner is prior 0, dyn_k = 1
        if (tid == 0) {
            int idx = b * NN;
            atomicAdd(&match_count[idx], 1);
            match_g[idx]   = g;
            match_iou[idx] = 0.0f;
        }
        return;
    }

    int lab = gt_labels[bg];

    // register mini-lists (capacity 4 = max candidates/thread at M<=1024)
    u64 zs = ((u64)0x80000000u << 32) | (0x10000u + (unsigned)tid * 4u); // iou 0.0, unique fake n
    u64 iK0 = zs, iK1 = zs + 1, iK2 = zs + 2, iK3 = zs + 3;  // descending iou keys
    u64 cK0 = ~0ull, cK1 = ~0ull, cK2 = ~0ull, cK3 = ~0ull;  // ascending cost keys
    float cP0 = 0.f, cP1 = 0.f, cP2 = 0.f, cP3 = 0.f;        // piou paired with cK

    for (int m = tid; m < M; m += 256) {
        int n = s_list[m];
        float4 pr = *reinterpret_cast<const float4*>(priors + (size_t)n * 4);
        float4 pb = *reinterpret_cast<const float4*>(pred_bboxes + ((size_t)b * NN + n) * 4);
        float lg = pred_scores[((size_t)b * NN + n) * CC + lab];
        float cost, piou;
        pair_cost_iou_inside(pr.x, pr.y, pr.z, pb.x, pb.y, pb.z, pb.w,
                             gb.x, gb.y, gb.z, gb.w, lg, flag, cost, piou);
        u64 ki = ((u64)f2u(piou) << 32) | (unsigned)n;
        if (ki > iK3) {
            iK3 = ki;
            if (iK3 > iK2) { u64 t0 = iK2; iK2 = iK3; iK3 = t0; }
            if (iK2 > iK1) { u64 t0 = iK1; iK1 = iK2; iK2 = t0; }
            if (iK1 > iK0) { u64 t0 = iK0; iK0 = iK1; iK1 = t0; }
        }
        u64 kc = ((u64)f2u(cost) << 32) | (unsigned)n;
        if (kc < cK3) {
            cK3 = kc; cP3 = piou;
            if (cK3 < cK2) { u64 t0 = cK2; cK2 = cK3; cK3 = t0; float f0 = cP2; cP2 = cP3; cP3 = f0; }
            if (cK2 < cK1) { u64 t0 = cK1; cK1 = cK2; cK2 = t0; float f0 = cP1; cP1 = cP2; cP2 = f0; }
            if (cK1 < cK0) { u64 t0 = cK0; cK0 = cK1; cK1 = t0; float f0 = cP0; cP0 = cP1; cP1 = f0; }
        }
    }

    // ---- Phase A: top-13 ious. Wave-local 13 rounds (no barriers), then
    // single-wave merge of 4x13 candidates. Keys unique -> single-lane pops.
    for (int r = 0; r < KTOP; ++r) {
        u64 h = iK0;
        #pragma unroll
        for (int off = 1; off < 64; off <<= 1) {
            u64 o = __shfl_xor(h, off, 64);
            if (o > h) h = o;
        }
        if (lane == 0) s_cand[w * KTOP + r] = h;
        if (iK0 == h) { iK0 = iK1; iK1 = iK2; iK2 = iK3; iK3 = 0ull; }
    }
    __syncthreads();
    if (w == 0) {
        u64 kk = (lane < 4 * KTOP) ? s_cand[lane] : 0ull;
        float ks = 0.0f;
        for (int r = 0; r < KTOP; ++r) {
            u64 h = kk;
            #pragma unroll
            for (int off = 1; off < 64; off <<= 1) {
                u64 o = __shfl_xor(h, off, 64);
                if (o > h) h = o;
            }
            ks += u2f((unsigned)(h >> 32));   // descending-order sum, matches top_k().sum(-1)
            if (kk == h) kk = 0ull;
        }
        if (lane == 0) { int dk = (int)ks; s_dynk = (dk < 1) ? 1 : dk; }
    }
    __syncthreads();
    int dyn_k = s_dynk;                    // dyn_k <= M guaranteed (|giou|<=1)

    // ---- Phase B: dyn_k smallest (cost, n). Same two-level structure.
    for (int r = 0; r < dyn_k; ++r) {
        u64 h = cK0;
        #pragma unroll
        for (int off = 1; off < 64; off <<= 1) {
            u64 o = __shfl_xor(h, off, 64);
            if (o < h) h = o;
        }
        if (cK0 == h) {                    // winner lane (unique unless sentinel)
            s_cand[w * KTOP + r]  = h;
            s_candP[w * KTOP + r] = cP0;
            cK0 = cK1; cP0 = cP1; cK1 = cK2; cP1 = cP2; cK2 = cK3; cP2 = cP3;
            cK3 = ~0ull;
        }
    }
    __syncthreads();
    if (w == 0) {
        int tot = 4 * dyn_k;
        u64 kk = ~0ull; float pp = 0.0f;
        if (lane < tot) {
            int wv = lane / dyn_k;
            int r  = lane - wv * dyn_k;
            kk = s_cand[wv * KTOP + r];
            pp = s_candP[wv * KTOP + r];
        }
        for (int r = 0; r < dyn_k; ++r) {
            u64 h = kk;
            #pragma unroll
            for (int off = 1; off < 64; off <<= 1) {
                u64 o = __shfl_xor(h, off, 64);
                if (o < h) h = o;
            }
            if (kk == h && h != ~0ull) {   // global r-th smallest -> scatter
                int bi = (int)(h & 0xffffffffu);
                int idx = b * NN + bi;
                atomicAdd(&match_count[idx], 1);
                match_g[idx]   = g;        // valid only when final count==1
                match_iou[idx] = pp;
                kk = ~0ull;
            }
        }
    }
}

// K2: fused resolve. cnt<=1 via table lookup; cnt>1 handled wave-cooperatively
// (expected ~1.2 multis per wave), replacing the old k2b kernel.
__global__ __launch_bounds__(256) void k2_resolve(
    const float* __restrict__ pred_bboxes,
    const float* __restrict__ pred_scores,
    const float* __restrict__ priors,
    const int*   __restrict__ gt_labels,
    const float* __restrict__ gt_bboxes,
    const float* __restrict__ pad_flag,
    const int*   __restrict__ match_count,
    const int*   __restrict__ match_g,
    const float* __restrict__ match_iou,
    int*   __restrict__ r_lab,
    float* __restrict__ r_miou,
    int*   __restrict__ class_num,
    float* __restrict__ out)
{
    int i = blockIdx.x * 256 + threadIdx.x;   // grid exact: 134400/256 = 525
    int lane = threadIdx.x & 63;
    int cnt = match_count[i];
    int b = i / NN;

    int lab = CC;
    float miou = 0.0f;
    float4 bbx = make_float4(0.0f, 0.0f, 0.0f, 0.0f);

    if (cnt == 1) {
        int g = match_g[i];
        int gi = b * GG + g;
        miou = match_iou[i];
        lab = gt_labels[gi];
        bbx = *reinterpret_cast<const float4*>(gt_bboxes + (size_t)gi * 4);
    }

    // wave-cooperative multi resolve: full-cost argmin over 100 gts, 2 slots/lane
    u64 mask = __ballot(cnt > 1);
    while (mask) {
        int src = __builtin_ctzll(mask);
        mask &= mask - 1;
        int ii = (i & ~63) | src;             // wave-aligned (256 % 64 == 0)
        int b2 = ii / NN, n2 = ii - b2 * NN;
        float4 pr = *reinterpret_cast<const float4*>(priors + (size_t)n2 * 4);
        float4 pb = *reinterpret_cast<const float4*>(pred_bboxes + (size_t)ii * 4);
        u64 bk = ~0ull; float bp = 0.0f;
        #pragma unroll
        for (int s = 0; s < 2; ++s) {
            int gg = lane + (s << 6);
            if (gg < GG) {
                int gi = b2 * GG + gg;
                float fl = pad_flag[gi];
                float4 gbx = *reinterpret_cast<const float4*>(gt_bboxes + (size_t)gi * 4);
                int lb = gt_labels[gi];
                float lg = pred_scores[(size_t)ii * CC + lb];
                float cost, piou;
                pair_cost_iou(pr.x, pr.y, pr.z, pb.x, pb.y, pb.z, pb.w,
                              gbx.x, gbx.y, gbx.z, gbx.w, lg, fl, cost, piou);
                u64 k = ((u64)f2u(cost) << 32) | (unsigned)gg;  // tie -> smallest g
                if (k < bk) { bk = k; bp = piou; }
            }
        }
        #pragma unroll
        for (int off = 1; off < 64; off <<= 1) {
            u64 ok = __shfl_xor(bk, off, 64);
            float op = __shfl_xor(bp, off, 64);
            if (ok < bk) { bk = ok; bp = op; }
        }
        if (lane == src) {                    // owner lane keeps the result
            int gw = (int)(bk & 0xffffffffu);
            int gi = b2 * GG + gw;
            lab = gt_labels[gi];
            miou = bp;
            bbx = *reinterpret_cast<const float4*>(gt_bboxes + (size_t)gi * 4);
        }
    }

    bool fg = cnt > 0;
    if (fg) atomicAdd(&class_num[lab], 1);
    r_lab[i]  = lab;
    r_miou[i] = miou;
    out[kO_LAB + i] = (float)lab;
    out[kO_FG  + i] = fg ? 1.0f : 0.0f;
    out[kO_MET + i] = miou;
    *reinterpret_cast<float4*>(out + kO_BB + (size_t)i * 4) = bbx;
}

// K35: block 0 = class weights (one wave); blocks 1..19 = area_dist (3,B,G).
__global__ __launch_bounds__(256) void k35_weights_area(
    const int*   __restrict__ class_num,
    float* __restrict__ dynw,
    const float* __restrict__ gt_area,
    const float* __restrict__ area_rule,
    const float* __restrict__ pad_flag,
    float* __restrict__ out)
{
    if (blockIdx.x == 0) {
        int lane = threadIdx.x;
        if (lane < 64) {
            int n0 = class_num[lane];
            int n1 = (lane < CC - 64) ? class_num[lane + 64] : 0;
            int m = max(n0, n1);
            #pragma unroll
            for (int off = 32; off > 0; off >>= 1) m = max(m, __shfl_down(m, off, 64));
            m = __shfl(m, 0, 64);
            float fm = (float)m;
            {
                float wv = (n0 > 0) ? fm / fmaxf((float)n0, 1.0f) : 1.0f;
                dynw[lane] = wv;
                out[kO_NUM  + lane] = (float)n0;
                out[kO_DYNW + lane] = wv;
            }
            if (lane < CC - 64) {
                float wv = (n1 > 0) ? fm / fmaxf((float)n1, 1.0f) : 1.0f;
                dynw[lane + 64] = wv;
                out[kO_NUM  + lane + 64] = (float)n1;
                out[kO_DYNW + lane + 64] = wv;
            }
        }
    } else {
        int idx = (blockIdx.x - 1) * 256 + threadIdx.x;
        if (idx < 3 * BB * GG) {
            int z = idx / (BB * GG);
            int rem = idx - z * (BB * GG);
            float ga = gt_area[rem];
            float lo = area_rule[z] * area_rule[z];
            float hi = area_rule[z + 1] * area_rule[z + 1];
            bool v = (ga >= lo) && (ga < hi) && (pad_flag[rem] > 0.0f);
            out[kO_AREA + idx] = v ? 1.0f : 0.0f;
        }
    }
}

// K4: fill assigned_scores + weights; float4 stores, u32 index math.
__global__ __launch_bounds__(256) void k4_fill(
    const int*   __restrict__ r_lab,
    const float* __restrict__ r_miou,
    const float* __restrict__ dynw,
    float* __restrict__ out)
{
    __shared__ float s_w[CC];
    if (threadIdx.x < CC) s_w[threadIdx.x] = dynw[threadIdx.x];
    __syncthreads();
    unsigned t = blockIdx.x * 256u + threadIdx.x;   // < 2,688,000 (grid exact)
    unsigned i = t / 20u;                            // const-div -> mulhi
    unsigned cq = (t - i * 20u) * 4u;
    int lab = r_lab[i];
    float miou = r_miou[i];
    bool fg = lab < CC;
    unsigned ulab = (unsigned)lab;
    float4 sc, wv;
    sc.x = (ulab == cq + 0u) ? miou : 0.0f;
    sc.y = (ulab == cq + 1u) ? miou : 0.0f;
    sc.z = (ulab == cq + 2u) ? miou : 0.0f;
    sc.w = (ulab == cq + 3u) ? miou : 0.0f;
    wv.x = fg ? s_w[cq + 0u] : 1.0f;
    wv.y = fg ? s_w[cq + 1u] : 1.0f;
    wv.z = fg ? s_w[cq + 2u] : 1.0f;
    wv.w = fg ? s_w[cq + 3u] : 1.0f;
    size_t base = (size_t)i * CC + cq;
    *reinterpret_cast<float4*>(out + kO_SC + base) = sc;
    *reinterpret_cast<float4*>(out + kO_W  + base) = wv;
}

extern "C" void kernel_launch(void* const* d_in, const int* in_sizes, int n_in,
                              void* d_out, int out_size, void* d_ws, size_t ws_size,
                              hipStream_t stream)
{
    const float* pred_bboxes = (const float*)d_in[0];
    const float* pred_scores = (const float*)d_in[1];
    const float* priors      = (const float*)d_in[2];
    const int*   gt_labels   = (const int*)d_in[3];
    const float* gt_bboxes   = (const float*)d_in[4];
    const float* pad_flag    = (const float*)d_in[5];
    const float* gt_area     = (const float*)d_in[6];
    const float* area_rule   = (const float*)d_in[7];
    float* out = (float*)d_out;

    // workspace: [match_count BB*NN][class_num CC] zeroed together
    char* w = (char*)d_ws;
    int*   match_count = (int*)w;   w += (size_t)BB * NN * 4;
    int*   class_num   = (int*)w;   w += (size_t)CC * 4;
    int*   match_g     = (int*)w;   w += (size_t)BB * NN * 4;
    float* match_iou   = (float*)w; w += (size_t)BB * NN * 4;
    int*   r_lab       = (int*)w;   w += (size_t)BB * NN * 4;
    float* r_miou      = (float*)w; w += (size_t)BB * NN * 4;
    float* dynw        = (float*)w; w += (size_t)CC * 4;

    hipMemsetAsync(d_ws, 0, (size_t)(BB * NN + CC) * 4, stream);

    k1_match<<<BB * GG, 256, 0, stream>>>(
        pred_bboxes, pred_scores, priors, gt_labels, gt_bboxes, pad_flag,
        match_count, match_g, match_iou);

    k2_resolve<<<BB * NN / 256, 256, 0, stream>>>(
        pred_bboxes, pred_scores, priors, gt_labels, gt_bboxes, pad_flag,
        match_count, match_g, match_iou, r_lab, r_miou, class_num, out);

    k35_weights_area<<<1 + (3 * BB * GG + 255) / 256, 256, 0, stream>>>(
        class_num, dynw, gt_area, area_rule, pad_flag, out);

    k4_fill<<<(int)((size_t)BB * NN * (CC / 4) / 256), 256, 0, stream>>>(
        r_lab, r_miou, dynw, out);
}

// Round 7
// 223.314 us; speedup vs baseline: 4.6331x; 1.0396x over previous
//
#include <hip/hip_runtime.h>

typedef unsigned long long u64;

#define BB 16
#define NN 8400
#define GG 100
#define CC 80
#define KTOP 13
#define EPSF 1e-7f
#define INFC 1e8f
#define MAXIN 1024                      // max inside priors per gt (real max ~500)

static constexpr size_t kO_LAB  = 0;
static constexpr size_t kO_W    = (size_t)BB * NN;               // 134400
static constexpr size_t kO_BB   = kO_W + (size_t)BB * NN * CC;   // 10886400
static constexpr size_t kO_SC   = kO_BB + (size_t)BB * NN * 4;   // 11424000
static constexpr size_t kO_MET  = kO_SC + (size_t)BB * NN * CC;  // 22176000
static constexpr size_t kO_FG   = kO_MET + (size_t)BB * NN;      // 22310400
static constexpr size_t kO_NUM  = kO_FG + (size_t)BB * NN;       // 22444800
static constexpr size_t kO_DYNW = kO_NUM + CC;                   // 22444880
static constexpr size_t kO_AREA = kO_DYNW + CC;                  // 22444960

// monotone float->uint mapping (total order matching float <)
__device__ __forceinline__ unsigned f2u(float x) {
    unsigned b = __float_as_uint(x);
    return (b & 0x80000000u) ? ~b : (b | 0x80000000u);
}
__device__ __forceinline__ float u2f(unsigned e) {
    return __uint_as_float((e & 0x80000000u) ? (e & 0x7fffffffu) : ~e);
}

// Full pair cost + piou for an INSIDE prior (is_in == flag > 0).
__device__ __forceinline__ void pair_cost_iou_inside(
    float px, float py, float st,
    float p0, float p1, float p2, float p3,
    float g0, float g1, float g2, float g3,
    float lg, float flag,
    float& cost, float& piou)
{
    float gcx = (g0 + g2) * 0.5f, gcy = (g1 + g3) * 0.5f;
    float dx = px - gcx, dy = py - gcy;
    float dist = sqrtf(dx * dx + dy * dy) / st * flag;
    float scp = exp2f((dist - 3.0f) * 3.32192809488736f) * flag;
    float ix1 = fmaxf(p0, g0), iy1 = fmaxf(p1, g1);
    float ix2 = fminf(p2, g2), iy2 = fminf(p3, g3);
    float ow = fmaxf(ix2 - ix1, 0.0f), oh = fmaxf(iy2 - iy1, 0.0f);
    float ov = ow * oh;
    float a1 = (p2 - p0) * (p3 - p1);
    float a2 = (g2 - g0) * (g3 - g1);
    float uni = fmaxf(a1 + a2 - ov, EPSF);
    float iou = ov / uni;
    float ex1 = fminf(p0, g0), ey1 = fminf(p1, g1);
    float ex2 = fmaxf(p2, g2), ey2 = fmaxf(p3, g3);
    float ew = fmaxf(ex2 - ex1, 0.0f), eh = fmaxf(ey2 - ey1, 0.0f);
    float enc = fmaxf(ew * eh, EPSF);
    float giou = iou - (enc - uni) / enc;
    piou = fabsf(giou * flag);
    float iou_cost = -__logf(piou + EPSF) * 3.0f;
    float sig = 1.0f / (1.0f + __expf(-lg));
    float sc = piou - sig;
    float asc = fabsf(sc);
    float bce = fmaxf(lg, 0.0f) - lg * piou + log1pf(__expf(-fabsf(lg)));
    float cls = bce * __expf(asc - 1.0f) * asc;
    cost = cls + iou_cost + scp;
}

// Full pair (any prior) — used by the fused multi-resolve in K2.
__device__ __forceinline__ void pair_cost_iou(
    float px, float py, float st,
    float p0, float p1, float p2, float p3,
    float g0, float g1, float g2, float g3,
    float lg, float flag,
    float& cost, float& piou)
{
    float l = px - g0, t = py - g1, r = g2 - px, d = g3 - py;
    float mn = fminf(fminf(l, t), fminf(r, d));
    float is_in = (mn > 0.0f) ? flag : 0.0f;
    float gcx = (g0 + g2) * 0.5f, gcy = (g1 + g3) * 0.5f;
    float dx = px - gcx, dy = py - gcy;
    float dist = sqrtf(dx * dx + dy * dy) / st * is_in;
    float scp = exp2f((dist - 3.0f) * 3.32192809488736f) * is_in;
    float ix1 = fmaxf(p0, g0), iy1 = fmaxf(p1, g1);
    float ix2 = fminf(p2, g2), iy2 = fminf(p3, g3);
    float ow = fmaxf(ix2 - ix1, 0.0f), oh = fmaxf(iy2 - iy1, 0.0f);
    float ov = ow * oh;
    float a1 = (p2 - p0) * (p3 - p1);
    float a2 = (g2 - g0) * (g3 - g1);
    float uni = fmaxf(a1 + a2 - ov, EPSF);
    float iou = ov / uni;
    float ex1 = fminf(p0, g0), ey1 = fminf(p1, g1);
    float ex2 = fmaxf(p2, g2), ey2 = fmaxf(p3, g3);
    float ew = fmaxf(ex2 - ex1, 0.0f), eh = fmaxf(ey2 - ey1, 0.0f);
    float enc = fmaxf(ew * eh, EPSF);
    float giou = iou - (enc - uni) / enc;
    piou = fabsf(giou * is_in);
    float iou_cost = -__logf(piou + EPSF) * 3.0f;
    float sig = 1.0f / (1.0f + __expf(-lg));
    float sc = piou - sig;
    float asc = fabsf(sc);
    float bce = fmaxf(lg, 0.0f) - lg * piou + log1pf(__expf(-fabsf(lg)));
    float cls = bce * __expf(asc - 1.0f) * asc;
    float cc = cls + iou_cost + scp;
    cost = (is_in > 0.0f) ? cc : INFC;
}

// K1: one workgroup per (b,g). Pass1 inside-test+compaction; pass2 full cost;
// selection via RANK COMPUTATION (broadcast LDS scans, zero shuffles):
//   riou  = #{(iou_i,n_i)  > (iou_j,n_j)}  -> s_top[riou] if riou < 13
//   rcost = #{(cost_i,n_i) < (cost_j,n_j)} -> match if rcost < dyn_k
// Rank-vs-threshold is exactly equivalent to the stable-argsort semantics.
__global__ __launch_bounds__(256) void k1_match(
    const float* __restrict__ pred_bboxes,
    const float* __restrict__ pred_scores,
    const float* __restrict__ priors,
    const int*   __restrict__ gt_labels,
    const float* __restrict__ gt_bboxes,
    const float* __restrict__ pad_flag,
    int*   __restrict__ match_count,
    int*   __restrict__ match_g,
    float* __restrict__ match_iou)
{
    __shared__ int   s_cnt;
    __shared__ int   s_list[MAXIN];
    __shared__ u64   s_kiou[MAXIN];
    __shared__ u64   s_kcost[MAXIN];
    __shared__ unsigned short s_rc[MAXIN];
    __shared__ float s_top[KTOP];

    int bg = blockIdx.x;
    int b = bg / GG, g = bg - b * GG;
    int tid = threadIdx.x;

    float flag = pad_flag[bg];
    if (flag == 0.0f) return;              // block-uniform exit

    if (tid == 0) s_cnt = 0;
    if (tid < KTOP) s_top[tid] = 0.0f;     // pad: top-13 includes 0s when M < 13
    __syncthreads();

    float4 gb = *reinterpret_cast<const float4*>(gt_bboxes + (size_t)bg * 4);

    // Pass 1: inside test + LDS compaction. 8400 = 32*256 + 208.
    #pragma unroll 4
    for (int k = 0; k < 32; ++k) {
        int n = tid + (k << 8);
        float4 p = *reinterpret_cast<const float4*>(priors + (size_t)n * 4);
        float mn = fminf(fminf(p.x - gb.x, p.y - gb.y),
                         fminf(gb.z - p.x, gb.w - p.y));
        if (mn > 0.0f) {
            int po = atomicAdd(&s_cnt, 1);
            if (po < MAXIN) s_list[po] = n;
        }
    }
    if (tid < NN - 8192) {
        int n = tid + 8192;
        float4 p = *reinterpret_cast<const float4*>(priors + (size_t)n * 4);
        float mn = fminf(fminf(p.x - gb.x, p.y - gb.y),
                         fminf(gb.z - p.x, gb.w - p.y));
        if (mn > 0.0f) {
            int po = atomicAdd(&s_cnt, 1);
            if (po < MAXIN) s_list[po] = n;
        }
    }
    __syncthreads();
    int M = min(s_cnt, MAXIN);

    if (M == 0) {
        // all costs INFC -> stable-rank winner is prior 0, dyn_k = 1
        if (tid == 0) {
            int idx = b * NN;
            atomicAdd(&match_count[idx], 1);
            match_g[idx]   = g;
            match_iou[idx] = 0.0f;
        }
        return;
    }

    int lab = gt_labels[bg];

    // Pass 2: full cost/piou on compacted set; publish sortable keys to LDS.
    for (int m = tid; m < M; m += 256) {
        int n = s_list[m];
        float4 pr = *reinterpret_cast<const float4*>(priors + (size_t)n * 4);
        float4 pb = *reinterpret_cast<const float4*>(pred_bboxes + ((size_t)b * NN + n) * 4);
        float lg = pred_scores[((size_t)b * NN + n) * CC + lab];
        float cost, piou;
        pair_cost_iou_inside(pr.x, pr.y, pr.z, pb.x, pb.y, pb.z, pb.w,
                             gb.x, gb.y, gb.z, gb.w, lg, flag, cost, piou);
        s_kiou[m]  = ((u64)f2u(piou) << 32) | (unsigned)n;
        s_kcost[m] = ((u64)f2u(cost) << 32) | (unsigned)n;
    }
    __syncthreads();

    // Rank scan: broadcast reads (all lanes read the same i -> no conflicts).
    for (int m = tid; m < M; m += 256) {
        u64 ki = s_kiou[m];
        u64 kc = s_kcost[m];
        int riou = 0, rcost = 0;
        #pragma unroll 4
        for (int i = 0; i < M; ++i) {
            riou  += (s_kiou[i]  > ki) ? 1 : 0;
            rcost += (s_kcost[i] < kc) ? 1 : 0;
        }
        if (riou < KTOP) s_top[riou] = u2f((unsigned)(ki >> 32));  // unique ranks
        s_rc[m] = (unsigned short)rcost;
    }
    __syncthreads();

    // dyn_k: descending-order sum of top-13 (same order as the reference)
    float ksum = 0.0f;
    #pragma unroll
    for (int r = 0; r < KTOP; ++r) ksum += s_top[r];
    int dyn_k = (int)ksum;                 // trunc; dyn_k <= M (|giou| < 1)
    if (dyn_k < 1) dyn_k = 1;

    // Scatter the dyn_k smallest-cost candidates.
    for (int m = tid; m < M; m += 256) {
        if ((int)s_rc[m] < dyn_k) {
            u64 ki = s_kiou[m];
            int n = (int)(ki & 0xffffffffu);
            int idx = b * NN + n;
            atomicAdd(&match_count[idx], 1);
            match_g[idx]   = g;            // valid only when final count==1
            match_iou[idx] = u2f((unsigned)(ki >> 32));
        }
    }
}

// K2: fused resolve. cnt<=1 via table lookup; cnt>1 handled wave-cooperatively.
__global__ __launch_bounds__(256) void k2_resolve(
    const float* __restrict__ pred_bboxes,
    const float* __restrict__ pred_scores,
    const float* __restrict__ priors,
    const int*   __restrict__ gt_labels,
    const float* __restrict__ gt_bboxes,
    const float* __restrict__ pad_flag,
    const int*   __restrict__ match_count,
    const int*   __restrict__ match_g,
    const float* __restrict__ match_iou,
    int*   __restrict__ r_lab,
    float* __restrict__ r_miou,
    int*   __restrict__ class_num,
    float* __restrict__ out)
{
    int i = blockIdx.x * 256 + threadIdx.x;   // grid exact: 134400/256 = 525
    int lane = threadIdx.x & 63;
    int cnt = match_count[i];
    int b = i / NN;

    int lab = CC;
    float miou = 0.0f;
    float4 bbx = make_float4(0.0f, 0.0f, 0.0f, 0.0f);

    if (cnt == 1) {
        int g = match_g[i];
        int gi = b * GG + g;
        miou = match_iou[i];
        lab = gt_labels[gi];
        bbx = *reinterpret_cast<const float4*>(gt_bboxes + (size_t)gi * 4);
    }

    // wave-cooperative multi resolve: full-cost argmin over 100 gts, 2 slots/lane
    u64 mask = __ballot(cnt > 1);
    while (mask) {
        int src = __builtin_ctzll(mask);
        mask &= mask - 1;
        int ii = (i & ~63) | src;             // wave-aligned (256 % 64 == 0)
        int b2 = ii / NN, n2 = ii - b2 * NN;
        float4 pr = *reinterpret_cast<const float4*>(priors + (size_t)n2 * 4);
        float4 pb = *reinterpret_cast<const float4*>(pred_bboxes + (size_t)ii * 4);
        u64 bk = ~0ull; float bp = 0.0f;
        #pragma unroll
        for (int s = 0; s < 2; ++s) {
            int gg = lane + (s << 6);
            if (gg < GG) {
                int gi = b2 * GG + gg;
                float fl = pad_flag[gi];
                float4 gbx = *reinterpret_cast<const float4*>(gt_bboxes + (size_t)gi * 4);
                int lb = gt_labels[gi];
                float lg = pred_scores[(size_t)ii * CC + lb];
                float cost, piou;
                pair_cost_iou(pr.x, pr.y, pr.z, pb.x, pb.y, pb.z, pb.w,
                              gbx.x, gbx.y, gbx.z, gbx.w, lg, fl, cost, piou);
                u64 k = ((u64)f2u(cost) << 32) | (unsigned)gg;  // tie -> smallest g
                if (k < bk) { bk = k; bp = piou; }
            }
        }
        #pragma unroll
        for (int off = 1; off < 64; off <<= 1) {
            u64 ok = __shfl_xor(bk, off, 64);
            float op = __shfl_xor(bp, off, 64);
            if (ok < bk) { bk = ok; bp = op; }
        }
        if (lane == src) {                    // owner lane keeps the result
            int gw = (int)(bk & 0xffffffffu);
            int gi = b2 * GG + gw;
            lab = gt_labels[gi];
            miou = bp;
            bbx = *reinterpret_cast<const float4*>(gt_bboxes + (size_t)gi * 4);
        }
    }

    bool fg = cnt > 0;
    if (fg) atomicAdd(&class_num[lab], 1);
    r_lab[i]  = lab;
    r_miou[i] = miou;
    out[kO_LAB + i] = (float)lab;
    out[kO_FG  + i] = fg ? 1.0f : 0.0f;
    out[kO_MET + i] = miou;
    *reinterpret_cast<float4*>(out + kO_BB + (size_t)i * 4) = bbx;
}

// K4: fill assigned_scores + weights; every block recomputes dynw from
// class_num (cheap, removes a kernel node). Extra blocks: area / NUM / DYNW.
#define K4MAIN ((BB * NN * (CC / 4)) / 256)    // 10500
__global__ __launch_bounds__(256) void k4_fill(
    const int*   __restrict__ r_lab,
    const float* __restrict__ r_miou,
    const int*   __restrict__ class_num,
    const float* __restrict__ gt_area,
    const float* __restrict__ area_rule,
    const float* __restrict__ pad_flag,
    float* __restrict__ out)
{
    __shared__ float s_w[CC];
    int t0 = threadIdx.x;
    if (t0 < 64) {
        int n0 = class_num[t0];
        int n1 = (t0 < CC - 64) ? class_num[t0 + 64] : 0;
        int m = max(n0, n1);
        #pragma unroll
        for (int off = 32; off > 0; off >>= 1) m = max(m, __shfl_down(m, off, 64));
        m = __shfl(m, 0, 64);
        float fm = (float)m;
        s_w[t0] = (n0 > 0) ? fm / fmaxf((float)n0, 1.0f) : 1.0f;
        if (t0 < CC - 64)
            s_w[t0 + 64] = (n1 > 0) ? fm / fmaxf((float)n1, 1.0f) : 1.0f;
    }
    __syncthreads();

    unsigned bid = blockIdx.x;
    if (bid < K4MAIN) {
        unsigned t = bid * 256u + threadIdx.x;   // < 2,688,000 (grid exact)
        unsigned i = t / 20u;                    // const-div -> mulhi
        unsigned cq = (t - i * 20u) * 4u;
        int lab = r_lab[i];
        float miou = r_miou[i];
        bool fg = lab < CC;
        unsigned ulab = (unsigned)lab;
        float4 sc, wv;
        sc.x = (ulab == cq + 0u) ? miou : 0.0f;
        sc.y = (ulab == cq + 1u) ? miou : 0.0f;
        sc.z = (ulab == cq + 2u) ? miou : 0.0f;
        sc.w = (ulab == cq + 3u) ? miou : 0.0f;
        wv.x = fg ? s_w[cq + 0u] : 1.0f;
        wv.y = fg ? s_w[cq + 1u] : 1.0f;
        wv.z = fg ? s_w[cq + 2u] : 1.0f;
        wv.w = fg ? s_w[cq + 3u] : 1.0f;
        size_t base = (size_t)i * CC + cq;
        *reinterpret_cast<float4*>(out + kO_SC + base) = sc;
        *reinterpret_cast<float4*>(out + kO_W  + base) = wv;
    } else {
        int idx = (int)(bid - K4MAIN) * 256 + threadIdx.x;
        if (idx < 3 * BB * GG) {
            int z = idx / (BB * GG);
            int rem = idx - z * (BB * GG);
            float ga = gt_area[rem];
            float lo = area_rule[z] * area_rule[z];
            float hi = area_rule[z + 1] * area_rule[z + 1];
            bool v = (ga >= lo) && (ga < hi) && (pad_flag[rem] > 0.0f);
            out[kO_AREA + idx] = v ? 1.0f : 0.0f;
        } else if (idx < 3 * BB * GG + CC) {
            int c = idx - 3 * BB * GG;
            out[kO_NUM + c] = (float)class_num[c];
        } else if (idx < 3 * BB * GG + 2 * CC) {
            int c = idx - 3 * BB * GG - CC;
            out[kO_DYNW + c] = s_w[c];
        }
    }
}

extern "C" void kernel_launch(void* const* d_in, const int* in_sizes, int n_in,
                              void* d_out, int out_size, void* d_ws, size_t ws_size,
                              hipStream_t stream)
{
    const float* pred_bboxes = (const float*)d_in[0];
    const float* pred_scores = (const float*)d_in[1];
    const float* priors      = (const float*)d_in[2];
    const int*   gt_labels   = (const int*)d_in[3];
    const float* gt_bboxes   = (const float*)d_in[4];
    const float* pad_flag    = (const float*)d_in[5];
    const float* gt_area     = (const float*)d_in[6];
    const float* area_rule   = (const float*)d_in[7];
    float* out = (float*)d_out;

    // workspace: [match_count BB*NN][class_num CC] zeroed together
    char* w = (char*)d_ws;
    int*   match_count = (int*)w;   w += (size_t)BB * NN * 4;
    int*   class_num   = (int*)w;   w += (size_t)CC * 4;
    int*   match_g     = (int*)w;   w += (size_t)BB * NN * 4;
    float* match_iou   = (float*)w; w += (size_t)BB * NN * 4;
    int*   r_lab       = (int*)w;   w += (size_t)BB * NN * 4;
    float* r_miou      = (float*)w; w += (size_t)BB * NN * 4;

    hipMemsetAsync(d_ws, 0, (size_t)(BB * NN + CC) * 4, stream);

    k1_match<<<BB * GG, 256, 0, stream>>>(
        pred_bboxes, pred_scores, priors, gt_labels, gt_bboxes, pad_flag,
        match_count, match_g, match_iou);

    k2_resolve<<<BB * NN / 256, 256, 0, stream>>>(
        pred_bboxes, pred_scores, priors, gt_labels, gt_bboxes, pad_flag,
        match_count, match_g, match_iou, r_lab, r_miou, class_num, out);

    k4_fill<<<K4MAIN + (3 * BB * GG + 2 * CC + 255) / 256, 256, 0, stream>>>(
        r_lab, r_miou, class_num, gt_area, area_rule, pad_flag, out);
}